// Round 17
// baseline (2130.374 us; speedup 1.0000x reference)
//
#include <hip/hip_runtime.h>
#include <stdint.h>

#define NT   8192
#define DI   2048
#define DH   16384
#define DO   2048
#define KSEL 64
#define EPS_SEL 0.004f
#define BCAP 256

typedef _Float16 f16;
typedef f16  f16x8 __attribute__((ext_vector_type(8)));
typedef float f32x4 __attribute__((ext_vector_type(4)));
typedef unsigned short usx8 __attribute__((ext_vector_type(8)));

__device__ __forceinline__ unsigned short f2h_bits(float x){
  f16 h = (f16)x;
  union { f16 h; unsigned short u; } c; c.h = h; return c.u;
}
__device__ __forceinline__ float h_bits2f(unsigned short u){
  union { unsigned short u; f16 h; } c; c.u = u; return (float)c.h;
}
__device__ __forceinline__ unsigned char f2fp8(float x){
  return (unsigned char)(__builtin_amdgcn_cvt_pk_fp8_f32(x, 0.f, 0u, false) & 0xff);
}

__device__ __forceinline__ void gload16(const void* g, void* lds){
  __builtin_amdgcn_global_load_lds(
    (const __attribute__((address_space(1))) void*)(uintptr_t)g,
    (__attribute__((address_space(3))) void*)(uint32_t)(uintptr_t)lds,
    16, 0, 0);
}

// ---------------- f32 -> f16 convert (vector8) ----------------
__global__ __launch_bounds__(256) void k_cvt(const float* __restrict__ in,
                                             unsigned short* __restrict__ out, int n8)
{
  int i = blockIdx.x*256 + threadIdx.x;
  if (i >= n8) return;
  const float4* p = (const float4*)in + (size_t)i*2;
  float4 a = p[0], b = p[1];
  union { f16 h[8]; usx8 u; } r;
  r.h[0]=(f16)a.x; r.h[1]=(f16)a.y; r.h[2]=(f16)a.z; r.h[3]=(f16)a.w;
  r.h[4]=(f16)b.x; r.h[5]=(f16)b.y; r.h[6]=(f16)b.z; r.h[7]=(f16)b.w;
  ((usx8*)out)[i] = r.u;
}

// -------- W_dec [DO][DH] f32 -> WdecT8 [DH][DO] fp8 e4m3, pre-scaled x64 -----
__global__ __launch_bounds__(256) void k_transpose_cvt8(const float* __restrict__ W,
                                                        unsigned char* __restrict__ WT)
{
  __shared__ unsigned char t[64][68];
  const int r0 = blockIdx.x*64;   // over DO
  const int c0 = blockIdx.y*64;   // over DH
  const int tid = threadIdx.x;
  const int q = tid >> 6, s = tid & 63;
#pragma unroll
  for (int i=0;i<16;i++){
    int r = q + i*4;
    t[r][s] = f2fp8(W[(size_t)(r0+r)*DH + c0 + s] * 64.0f);
  }
  __syncthreads();
#pragma unroll
  for (int i=0;i<16;i++){
    int c = q + i*4;
    WT[(size_t)(c0+c)*DO + r0 + s] = t[s][c];
  }
}

// ======== 256^2 8-phase GEMM (m201 + R12 single-barrier + R15 frag prefetch) ==
// Fragment loads software-pipelined one phase ahead into a SECOND named frag
// set (arE/arO, brE/brO; set per LOAD, all compile-time). Before MFMA(k):
// s_waitcnt lgkmcnt(M), M = prefetch reads just issued (in-order DS completion
// drains exactly phase-k's frags). MFMA(k) overlaps the LDS service of phase
// k+1's reads -> phase ~max(LDS, MFMA) instead of their sum. Hazard ledger:
// all (stage, prefetch) pairs at drift<=1 touch disjoint {A,B}x{half}x{buf}
// regions; VM6/VM0 pre-barrier placements cover every first read.
template<bool F16OUT, bool HASB2>
__device__ __forceinline__ void gemm8_body(
    const unsigned short* __restrict__ Ap,
    const unsigned short* __restrict__ Bp,
    const float* __restrict__ bias1,
    const float* __restrict__ bias2,
    void* __restrict__ Cout, int N)
{
  __shared__ unsigned short lds[65536];   // 128 KB
  const int tid  = threadIdx.x;
  const int lane = tid & 63;
  const int wv   = tid >> 6;
  const int wm   = wv >> 2;     // 0..1
  const int wn   = wv & 3;      // 0..3
  const int bm   = blockIdx.x;  // fastest -> B-panel reuse (R5-proven)
  const int bn   = blockIdx.y;
  const int fr   = lane & 15;
  const int fq   = lane >> 4;

  f32x4 acc[8][4];
#pragma unroll
  for (int i=0;i<8;i++)
#pragma unroll
    for (int j=0;j<4;j++) acc[i][j] = (f32x4){0.f,0.f,0.f,0.f};

  // two named fragment sets (compile-time selection; no runtime indexing)
  f16x8 arE[4][2], arO[4][2];
  f16x8 brE[2][2], brO[2][2];

#define STAGE_HALF(t, ab, h) do { \
    const unsigned short* G_ = (ab) ? Bp : Ap; \
    const int rb_ = ((ab) ? bn : bm)*256 + (h)*128; \
    const int k0_ = (t)*64; \
    const int db_ = ((t)&1)*32768 + (ab)*16384 + (h)*8192; \
    _Pragma("unroll") \
    for (int is_=0; is_<2; ++is_){ \
      const int cw_ = wv*64 + is_*512; \
      const int cl_ = cw_ + lane; \
      const int cs_ = cl_ ^ ((cl_>>3)&7); \
      gload16(G_ + (size_t)(rb_ + (cs_>>3))*DI + k0_ + (cs_&7)*8, \
              (unsigned short*)lds + db_ + cw_*8); \
    } } while(0)

#define LD_A(S, buf, mh) do { \
    const int ba_ = (buf)*32768 + (mh)*8192; \
    _Pragma("unroll") \
    for (int mf_=0; mf_<4; ++mf_) \
    _Pragma("unroll") \
    for (int ks_=0; ks_<2; ++ks_){ \
      const int lin_ = (wm*64 + mf_*16 + fr)*128 + (ks_*4 + fq)*16; \
      const int sz_  = lin_ ^ ((((lin_>>7)&7))<<4); \
      ar##S[mf_][ks_] = *(const f16x8*)&lds[ba_ + (sz_>>1)]; \
    } } while(0)

#define LD_B(S, buf, nh) do { \
    const int bb_ = (buf)*32768 + 16384 + (nh)*8192; \
    _Pragma("unroll") \
    for (int nf_=0; nf_<2; ++nf_) \
    _Pragma("unroll") \
    for (int ks_=0; ks_<2; ++ks_){ \
      const int lin_ = (wn*32 + nf_*16 + fr)*128 + (ks_*4 + fq)*16; \
      const int sz_  = lin_ ^ ((((lin_>>7)&7))<<4); \
      br##S[nf_][ks_] = *(const f16x8*)&lds[bb_ + (sz_>>1)]; \
    } } while(0)

#define MM(AS, BS, mh, nh) do { \
    _Pragma("unroll") \
    for (int mf_=0; mf_<4; ++mf_) \
    _Pragma("unroll") \
    for (int nf_=0; nf_<2; ++nf_) \
    _Pragma("unroll") \
    for (int ks_=0; ks_<2; ++ks_) \
      acc[(mh)*4+mf_][(nh)*2+nf_] = __builtin_amdgcn_mfma_f32_16x16x32_f16( \
          ar##AS[mf_][ks_], br##BS[nf_][ks_], acc[(mh)*4+mf_][(nh)*2+nf_], 0, 0, 0); \
  } while(0)

#define VM6 asm volatile("s_waitcnt vmcnt(6)" ::: "memory")
#define VM0 asm volatile("s_waitcnt vmcnt(0)" ::: "memory")

// phase body: VM?; barrier; prefetch next-phase frags (PRE = statement seq);
// stage; counted lgkm (drains THIS phase's frags, leaves prefetch in flight);
// MFMA.
#define PHX(AS, BS, mh, nh, PRE, STG, VM, LGN) do { \
    VM; \
    __builtin_amdgcn_s_barrier(); \
    PRE; \
    STG; \
    asm volatile("s_waitcnt lgkmcnt(" #LGN ")" ::: "memory"); \
    __builtin_amdgcn_sched_barrier(0); \
    __builtin_amdgcn_s_setprio(1); \
    MM(AS, BS, mh, nh); \
    __builtin_amdgcn_s_setprio(0); \
  } while(0)

#define NOP2 do {} while(0)

  // -------- prologue: tile0 all 4 halves + tile1 {A0,B1,A1}; preload ph1 -----
  STAGE_HALF(0,0,0); STAGE_HALF(0,1,1); STAGE_HALF(0,0,1); STAGE_HALF(0,1,0);
  STAGE_HALF(1,0,0); STAGE_HALF(1,1,1); STAGE_HALF(1,0,1);
  asm volatile("s_waitcnt vmcnt(6)" ::: "memory");  // tile0 fully landed
  __builtin_amdgcn_s_barrier();
  LD_A(E, 0, 0); LD_B(E, 0, 0);   // phase-1 frags (12 reads in flight)

  for (int j = 0; j < 15; ++j) {
    const int a = 2*j, b = 2*j+1;
    PHX(E,E, 0,0, LD_B(O,0,1),                STAGE_HALF(b,  1,0), NOP2, 4);
    PHX(E,O, 0,1, LD_A(O,0,1),                STAGE_HALF(a+2,0,0), NOP2, 8);
    PHX(O,O, 1,1, LD_B(E,0,0),                STAGE_HALF(a+2,1,1), NOP2, 4);
    PHX(O,E, 1,0, LD_A(E,1,0); LD_B(O,1,0),   STAGE_HALF(a+2,0,1), VM6, 12);
    PHX(E,O, 0,0, LD_B(E,1,1),                STAGE_HALF(a+2,1,0), NOP2, 4);
    PHX(E,E, 0,1, LD_A(O,1,1),                STAGE_HALF(b+2,0,0), NOP2, 8);
    PHX(O,E, 1,1, LD_B(O,1,0),                STAGE_HALF(b+2,1,1), NOP2, 4);
    PHX(O,O, 1,0, LD_A(E,0,0); LD_B(E,0,0),   STAGE_HALF(b+2,0,1), VM6, 12);
  }
  // -------- tail: tiles 30,31; only B0(31) left to stage --------
  PHX(E,E, 0,0, LD_B(O,0,1),                STAGE_HALF(31,1,0), NOP2, 4);
  PHX(E,O, 0,1, LD_A(O,0,1),                NOP2,               NOP2, 8);
  PHX(O,O, 1,1, LD_B(E,0,0),                NOP2,               NOP2, 4);
  PHX(O,E, 1,0, LD_A(E,1,0); LD_B(O,1,0),   NOP2,               VM0, 12);
  PHX(E,O, 0,0, LD_B(E,1,1),                NOP2,               NOP2, 4);
  PHX(E,E, 0,1, LD_A(O,1,1),                NOP2,               NOP2, 8);
  PHX(O,E, 1,1, LD_B(O,1,0),                NOP2,               NOP2, 4);
  PHX(O,O, 1,0, NOP2,                       NOP2,               NOP2, 0);

#undef NOP2
#undef PHX
#undef VM6
#undef VM0
#undef MM
#undef LD_B
#undef LD_A
#undef STAGE_HALF

  // direct-store epilogue (R8/R9-proven)
#pragma unroll
  for (int nh=0; nh<2; ++nh)
#pragma unroll
  for (int nf=0; nf<2; ++nf){
    const int col = bn*256 + nh*128 + wn*32 + nf*16 + fr;
    float bs = bias1[col];
    if (HASB2) bs += bias2[col];
#pragma unroll
    for (int mh=0; mh<2; ++mh)
#pragma unroll
    for (int mf=0; mf<4; ++mf){
      const int row0 = bm*256 + mh*128 + wm*64 + mf*16 + fq*4;
#pragma unroll
      for (int q=0; q<4; ++q){
        float v = acc[mh*4+mf][nh*2+nf][q] + bs;
        if (F16OUT) ((unsigned short*)Cout)[(size_t)(row0+q)*N + col] = f2h_bits(v);
        else        ((float*)Cout)[(size_t)(row0+q)*N + col] = v;
      }
    }
  }
}

__global__ __launch_bounds__(512, 2) void k_gemm_enc8(
    const unsigned short* __restrict__ Ap, const unsigned short* __restrict__ Bp,
    const float* __restrict__ bias, unsigned short* __restrict__ C)
{
  gemm8_body<true, false>(Ap, Bp, bias, nullptr, (void*)C, DH);
}

__global__ __launch_bounds__(512, 2) void k_gemm_skip8(
    const unsigned short* __restrict__ Ap, const unsigned short* __restrict__ Bp,
    const float* __restrict__ bias1, const float* __restrict__ bias2,
    float* __restrict__ C)
{
  gemm8_body<false, true>(Ap, Bp, bias1, bias2, (void*)C, DO);
}

// ---------------- exact top-64 per row (R12-proven version, byte-exact) -------
__global__ __launch_bounds__(256) void k_topk(
    const unsigned short* __restrict__ P,
    const float* __restrict__ X,
    const float* __restrict__ Wenc,
    const float* __restrict__ benc,
    int*   __restrict__ candIdx,
    float* __restrict__ candVal)
{
  __shared__ unsigned int hist8[8][257];   // padded stride
  __shared__ unsigned int hist2[257];
  __shared__ int   inIdx[64];
  __shared__ float inVal[64];
  __shared__ int    bandIdx[BCAP];
  __shared__ double bandVal[BCAP];
  __shared__ int s_inCnt, s_bandCnt, s_sel, s_above, s_sel2;

  const int r = blockIdx.x;
  const int tid = threadIdx.x;
  const int wv = tid >> 6, lane = tid & 63;
  const int lc = lane & 7;
  const unsigned short* Prow = P + (size_t)r*DH;

#pragma unroll
  for (int k=0;k<8;k++) hist8[k][tid] = 0;
  hist2[tid] = 0;
  if (tid==0){ s_inCnt=0; s_bandCnt=0; }

  // row -> 8 named registers (32 VGPR)
  const usx8* Pv = (const usx8*)Prow;
  usx8 c0 = Pv[tid];        usx8 c1 = Pv[tid+256];
  usx8 c2 = Pv[tid+512];    usx8 c3 = Pv[tid+768];
  usx8 c4 = Pv[tid+1024];   usx8 c5 = Pv[tid+1280];
  usx8 c6 = Pv[tid+1536];   usx8 c7 = Pv[tid+1792];
  __syncthreads();

#define OMAP(b) (unsigned short)(((b) & 0x8000) ? (unsigned short)~(b) : (unsigned short)((b)|0x8000))
#define H1(CC) { _Pragma("unroll") for (int e=0;e<8;e++){ \
    unsigned short o = OMAP(CC[e]); atomicAdd(&hist8[lc][o>>8], 1u); } }
  H1(c0) H1(c1) H1(c2) H1(c3) H1(c4) H1(c5) H1(c6) H1(c7)
#undef H1
  __syncthreads();
  {
    unsigned int hs = 0;
#pragma unroll
    for (int c=0;c<8;c++) hs += hist8[c][tid];
    hist8[0][tid] = hs;
  }
  __syncthreads();

  if (tid < 64) {
    const int h0 = 255 - 4*tid;
    unsigned int c0_=hist8[0][h0], c1_=hist8[0][h0-1], c2_=hist8[0][h0-2], c3_=hist8[0][h0-3];
    unsigned int s = c0_+c1_+c2_+c3_;
    unsigned int Pi = s;
#pragma unroll
    for (int off=1; off<64; off<<=1){
      unsigned int t = __shfl_up(Pi, off);
      if (tid >= off) Pi += t;
    }
    unsigned long long mk = __ballot(Pi >= KSEL);
    int cr = (int)__builtin_ctzll(mk);
    if (tid == cr){
      unsigned int cum = Pi - s;
      unsigned int cc[4] = {c0_,c1_,c2_,c3_};
#pragma unroll
      for (int j=0;j<4;j++){
        if (cum + cc[j] >= KSEL){ s_sel = h0-j; s_above = (int)cum; break; }
        cum += cc[j];
      }
    }
  }
  __syncthreads();
  const int bsel = s_sel; const int cntAbove = s_above;

#define H2(CC) { _Pragma("unroll") for (int e=0;e<8;e++){ \
    unsigned short o = OMAP(CC[e]); \
    if ((int)(o>>8) == bsel) atomicAdd(&hist2[o & 0xff], 1u); } }
  H2(c0) H2(c1) H2(c2) H2(c3) H2(c4) H2(c5) H2(c6) H2(c7)
#undef H2
  __syncthreads();
  {
    const int K2 = KSEL - cntAbove;
    if (tid < 64) {
      const int h0 = 255 - 4*tid;
      unsigned int c0_=hist2[h0], c1_=hist2[h0-1], c2_=hist2[h0-2], c3_=hist2[h0-3];
      unsigned int s = c0_+c1_+c2_+c3_;
      unsigned int Pi = s;
#pragma unroll
      for (int off=1; off<64; off<<=1){
        unsigned int t = __shfl_up(Pi, off);
        if (tid >= off) Pi += t;
      }
      unsigned long long mk = __ballot(Pi >= (unsigned)K2);
      int cr = (int)__builtin_ctzll(mk);
      if (tid == cr){
        unsigned int cum = Pi - s;
        unsigned int cc[4] = {c0_,c1_,c2_,c3_};
#pragma unroll
        for (int j=0;j<4;j++){
          if (cum + cc[j] >= (unsigned)K2){ s_sel2 = h0-j; break; }
          cum += cc[j];
        }
      }
    }
  }
  __syncthreads();

  unsigned short To = (unsigned short)((bsel<<8) | s_sel2);
  unsigned short tb = (To & 0x8000) ? (unsigned short)(To ^ 0x8000) : (unsigned short)~To;
  const float T = h_bits2f(tb);
  const float hiv = T + 2.0f*EPS_SEL, lov = T - 2.0f*EPS_SEL;

#define EXT(CC, KK) { _Pragma("unroll") for (int e=0;e<8;e++){ \
    float v = h_bits2f(CC[e]); \
    if (v > hiv){ \
      int p = atomicAdd(&s_inCnt,1); \
      if (p < 64){ inIdx[p] = (tid + (KK)*256)*8 + e; inVal[p] = v; } \
    } else if (v >= lov){ \
      int p = atomicAdd(&s_bandCnt,1); \
      if (p < BCAP) bandIdx[p] = (tid + (KK)*256)*8 + e; \
    } } }
  EXT(c0,0) EXT(c1,1) EXT(c2,2) EXT(c3,3) EXT(c4,4) EXT(c5,5) EXT(c6,6) EXT(c7,7)
#undef EXT
#undef OMAP
  __syncthreads();
  const int m = s_inCnt < 64 ? s_inCnt : 64;
  const int B = s_bandCnt < BCAP ? s_bandCnt : BCAP;

  // exact f64 recompute for ambiguous band (4-way ILP partial sums)
  const float* Xr = X + (size_t)r*DI;
  for (int b=wv; b<B; b+=4){
    const int j = bandIdx[b];
    const float* Wr = Wenc + (size_t)j*DI;
    double s0=0.0, s1=0.0, s2=0.0, s3=0.0;
    for (int k0=lane; k0<DI; k0+=256){
      s0 = fma((double)Xr[k0],     (double)Wr[k0],     s0);
      s1 = fma((double)Xr[k0+64],  (double)Wr[k0+64],  s1);
      s2 = fma((double)Xr[k0+128], (double)Wr[k0+128], s2);
      s3 = fma((double)Xr[k0+192], (double)Wr[k0+192], s3);
    }
    double s = (s0+s1)+(s2+s3);
#pragma unroll
    for (int off=32; off>=1; off>>=1) s += __shfl_down(s, off);
    if (lane==0) bandVal[b] = s + (double)benc[j];
  }
  __syncthreads();

  int* ci = candIdx + (size_t)r*KSEL;
  float* cv = candVal + (size_t)r*KSEL;
  for (int t=tid; t<m; t+=256){ ci[t]=inIdx[t]; cv[t]=inVal[t]; }

  const int need = KSEL - m;
  if (tid < 64 && need > 0){
    unsigned int used = 0;
    for (int t=0;t<need;t++){
      double best = -1.0e300; int bi = -1;
#pragma unroll
      for (int sIt=0;sIt<4;sIt++){
        int b = tid + sIt*64;
        if (b < B && !((used>>sIt)&1)){
          double v = bandVal[b];
          if (v > best){ best=v; bi=b; }
        }
      }
#pragma unroll
      for (int off=32; off>=1; off>>=1){
        double ov = __shfl_down(best, off);
        int    oi = __shfl_down(bi,   off);
        if (ov > best){ best = ov; bi = oi; }
      }
      bi   = __shfl(bi, 0);
      best = __shfl(best, 0);
      if ((bi & 63) == tid) used |= 1u << (bi >> 6);
      if (tid == 0){
        ci[m+t] = bandIdx[bi];
        cv[m+t] = (float)best;
      }
    }
  }
}

// ---------------- sparse decode (fp8 gather) + loss partial ----------------
__global__ __launch_bounds__(256) void k_decode(
    float* __restrict__ outhat,
    const unsigned char* __restrict__ WdT8,
    const int*   __restrict__ candIdx,
    const float* __restrict__ candVal,
    const float* __restrict__ target,
    float* __restrict__ lossPartial)
{
  __shared__ int   sIdx[KSEL];
  __shared__ float sVal[KSEL];
  __shared__ float wsum[4];
  const int r = blockIdx.x, tid = threadIdx.x;
  if (tid < KSEL){
    sIdx[tid]=candIdx[(size_t)r*KSEL+tid];
    float v=candVal[(size_t)r*KSEL+tid];
    sVal[tid] = (v>0.f ? v : 0.f) * 0.015625f;   // /64 descale
  }
  __syncthreads();
  float* orow = outhat + (size_t)r*DO;
  float a[8];
  {
    float4 v0 = *(const float4*)(orow + tid*8);
    float4 v1 = *(const float4*)(orow + tid*8 + 4);
    a[0]=v0.x;a[1]=v0.y;a[2]=v0.z;a[3]=v0.w;a[4]=v1.x;a[5]=v1.y;a[6]=v1.z;a[7]=v1.w;
  }
#pragma unroll 4
  for (int c=0;c<KSEL;c++){
    const float v = sVal[c];
    const uint2 w = *(const uint2*)(WdT8 + (size_t)sIdx[c]*DO + tid*8);
    a[0] = fmaf(v, __builtin_amdgcn_cvt_f32_fp8(w.x, 0), a[0]);
    a[1] = fmaf(v, __builtin_amdgcn_cvt_f32_fp8(w.x, 1), a[1]);
    a[2] = fmaf(v, __builtin_amdgcn_cvt_f32_fp8(w.x, 2), a[2]);
    a[3] = fmaf(v, __builtin_amdgcn_cvt_f32_fp8(w.x, 3), a[3]);
    a[4] = fmaf(v, __builtin_amdgcn_cvt_f32_fp8(w.y, 0), a[4]);
    a[5] = fmaf(v, __builtin_amdgcn_cvt_f32_fp8(w.y, 1), a[5]);
    a[6] = fmaf(v, __builtin_amdgcn_cvt_f32_fp8(w.y, 2), a[6]);
    a[7] = fmaf(v, __builtin_amdgcn_cvt_f32_fp8(w.y, 3), a[7]);
  }
  const float* trow = target + (size_t)r*DO;
  float4 t0 = *(const float4*)(trow + tid*8);
  float4 t1 = *(const float4*)(trow + tid*8 + 4);
  float tt[8] = {t0.x,t0.y,t0.z,t0.w,t1.x,t1.y,t1.z,t1.w};
  float ls = 0.f;
#pragma unroll
  for (int j=0;j<8;j++){ float d = a[j]-tt[j]; ls = fmaf(d,d,ls); }
  {
    float4 v0 = {a[0],a[1],a[2],a[3]}, v1 = {a[4],a[5],a[6],a[7]};
    *(float4*)(orow + tid*8) = v0;
    *(float4*)(orow + tid*8 + 4) = v1;
  }
#pragma unroll
  for (int off=32; off>=1; off>>=1) ls += __shfl_down(ls, off);
  if ((tid&63)==0) wsum[tid>>6]=ls;
  __syncthreads();
  if (tid==0)
    lossPartial[r] = (wsum[0]+wsum[1]+wsum[2]+wsum[3]) * (1.0f/((float)NT*(float)DO));
}

__global__ __launch_bounds__(256) void k_lossreduce(const float* __restrict__ lp,
                                                    float* __restrict__ out)
{
  __shared__ double ws[4];
  double s=0.0;
  for (int i=threadIdx.x;i<NT;i+=256) s += (double)lp[i];
#pragma unroll
  for (int off=32; off>=1; off>>=1) s += __shfl_down(s, off);
  if ((threadIdx.x&63)==0) ws[threadIdx.x>>6]=s;
  __syncthreads();
  if (threadIdx.x==0) *out = (float)(ws[0]+ws[1]+ws[2]+ws[3]);
}

// ---------------- finalize h: zero + scatter ----------------
__global__ __launch_bounds__(256) void k_scatter(
    float* __restrict__ H, const int* __restrict__ candIdx, const float* __restrict__ candVal)
{
  const int r=blockIdx.x, tid=threadIdx.x;
  float* hr = H + (size_t)r*DH;
  const float4 z = {0.f,0.f,0.f,0.f};
#pragma unroll
  for (int i=0;i<16;i++) ((float4*)hr)[tid + i*256] = z;
  __syncthreads();
  if (tid<KSEL){
    float v = candVal[(size_t)r*KSEL+tid];
    hr[candIdx[(size_t)r*KSEL+tid]] = v>0.f ? v : 0.f;
  }
}

extern "C" void kernel_launch(void* const* d_in, const int* in_sizes, int n_in,
                              void* d_out, int out_size, void* d_ws, size_t ws_size,
                              hipStream_t stream)
{
  const float* X     = (const float*)d_in[0];
  const float* tgt   = (const float*)d_in[1];
  const float* Wenc  = (const float*)d_in[2];
  const float* benc  = (const float*)d_in[3];
  const float* Wdec  = (const float*)d_in[4];
  const float* bdec  = (const float*)d_in[5];
  const float* Wskip = (const float*)d_in[6];
  const float* bskip = (const float*)d_in[7];

  float* out     = (float*)d_out;
  float* outhat  = out;
  float* H       = out + (size_t)NT*DO;
  float* lossOut = out + (size_t)NT*DO + (size_t)NT*DH;

  // h-region scratch plan (dead until k_scatter)
  char* hb = (char*)H;
  unsigned short* P      = (unsigned short*)hb;
  char* U                = hb + (size_t)NT*DH*2;
  unsigned short* Xh     = (unsigned short*)U;
  unsigned short* Wench  = (unsigned short*)(U + (size_t)NT*DI*2);
  unsigned short* Wskiph = (unsigned short*)(U + (size_t)NT*DI*2 + (size_t)DH*DI*2);
  unsigned char*  WdT8   = (unsigned char*)(U + (size_t)NT*DI*2 + (size_t)DH*DI*2 + (size_t)DO*DI*2);

  int*   candIdx    = (int*)d_ws;
  float* candVal    = (float*)((char*)d_ws + (size_t)NT*KSEL*4);
  float* lossPartial= (float*)((char*)d_ws + (size_t)NT*KSEL*8);

  k_cvt<<<NT*DI/8/256, 256, 0, stream>>>(X, Xh, NT*DI/8);
  k_cvt<<<DH*DI/8/256, 256, 0, stream>>>(Wenc, Wench, DH*DI/8);
  k_cvt<<<DO*DI/8/256, 256, 0, stream>>>(Wskip, Wskiph, DO*DI/8);
  k_transpose_cvt8<<<dim3(DO/64, DH/64), 256, 0, stream>>>(Wdec, WdT8);

  k_gemm_enc8<<<dim3(NT/256, DH/256), 512, 0, stream>>>(Xh, Wench, benc, P);
  k_topk<<<NT, 256, 0, stream>>>(P, X, Wenc, benc, candIdx, candVal);
  k_gemm_skip8<<<dim3(NT/256, DO/256), 512, 0, stream>>>(Xh, Wskiph, bdec, bskip, outhat);
  k_decode<<<NT, 256, 0, stream>>>(outhat, WdT8, candIdx, candVal, tgt, lossPartial);
  k_lossreduce<<<1, 256, 0, stream>>>(lossPartial, lossOut);
  k_scatter<<<NT, 256, 0, stream>>>(H, candIdx, candVal);
}

// Round 18
// 1151.814 us; speedup vs baseline: 1.8496x; 1.8496x over previous
//
#include <hip/hip_runtime.h>
#include <stdint.h>

#define NT   8192
#define DI   2048
#define DH   16384
#define DO   2048
#define KSEL 64
#define EPS_SEL 0.004f
#define BCAP 256

typedef _Float16 f16;
typedef f16  f16x8 __attribute__((ext_vector_type(8)));
typedef float f32x4 __attribute__((ext_vector_type(4)));
typedef unsigned short usx8 __attribute__((ext_vector_type(8)));

__device__ __forceinline__ unsigned short f2h_bits(float x){
  f16 h = (f16)x;
  union { f16 h; unsigned short u; } c; c.h = h; return c.u;
}
__device__ __forceinline__ float h_bits2f(unsigned short u){
  union { unsigned short u; f16 h; } c; c.u = u; return (float)c.h;
}
__device__ __forceinline__ unsigned char f2fp8(float x){
  return (unsigned char)(__builtin_amdgcn_cvt_pk_fp8_f32(x, 0.f, 0u, false) & 0xff);
}

__device__ __forceinline__ void gload16(const void* g, void* lds){
  __builtin_amdgcn_global_load_lds(
    (const __attribute__((address_space(1))) void*)(uintptr_t)g,
    (__attribute__((address_space(3))) void*)(uint32_t)(uintptr_t)lds,
    16, 0, 0);
}

// ---------------- f32 -> f16 convert (vector8) ----------------
__global__ __launch_bounds__(256) void k_cvt(const float* __restrict__ in,
                                             unsigned short* __restrict__ out, int n8)
{
  int i = blockIdx.x*256 + threadIdx.x;
  if (i >= n8) return;
  const float4* p = (const float4*)in + (size_t)i*2;
  float4 a = p[0], b = p[1];
  union { f16 h[8]; usx8 u; } r;
  r.h[0]=(f16)a.x; r.h[1]=(f16)a.y; r.h[2]=(f16)a.z; r.h[3]=(f16)a.w;
  r.h[4]=(f16)b.x; r.h[5]=(f16)b.y; r.h[6]=(f16)b.z; r.h[7]=(f16)b.w;
  ((usx8*)out)[i] = r.u;
}

// -------- W_dec [DO][DH] f32 -> WdecT8 [DH][DO] fp8 e4m3, pre-scaled x64 -----
__global__ __launch_bounds__(256) void k_transpose_cvt8(const float* __restrict__ W,
                                                        unsigned char* __restrict__ WT)
{
  __shared__ unsigned char t[64][68];
  const int r0 = blockIdx.x*64;   // over DO
  const int c0 = blockIdx.y*64;   // over DH
  const int tid = threadIdx.x;
  const int q = tid >> 6, s = tid & 63;
#pragma unroll
  for (int i=0;i<16;i++){
    int r = q + i*4;
    t[r][s] = f2fp8(W[(size_t)(r0+r)*DH + c0 + s] * 64.0f);
  }
  __syncthreads();
#pragma unroll
  for (int i=0;i<16;i++){
    int c = q + i*4;
    WT[(size_t)(c0+c)*DO + r0 + s] = t[s][c];
  }
}

// ============ 256^2 8-phase GEMM template (R14-proven: m201 + R12 single
// barrier; NO fragment prefetch — R16 proved the second frag set exceeds the
// ~256-reg/wave budget at this occupancy and spills ~1GB to scratch) =========
template<bool F16OUT, bool HASB2>
__device__ __forceinline__ void gemm8_body(
    const unsigned short* __restrict__ Ap,
    const unsigned short* __restrict__ Bp,
    const float* __restrict__ bias1,
    const float* __restrict__ bias2,
    void* __restrict__ Cout, int N)
{
  __shared__ unsigned short lds[65536];   // 128 KB
  const int tid  = threadIdx.x;
  const int lane = tid & 63;
  const int wv   = tid >> 6;
  const int wm   = wv >> 2;     // 0..1
  const int wn   = wv & 3;      // 0..3
  const int bm   = blockIdx.x;  // fastest -> B-panel reuse (R5-proven)
  const int bn   = blockIdx.y;
  const int fr   = lane & 15;
  const int fq   = lane >> 4;

  f32x4 acc[8][4];
#pragma unroll
  for (int i=0;i<8;i++)
#pragma unroll
    for (int j=0;j<4;j++) acc[i][j] = (f32x4){0.f,0.f,0.f,0.f};

  f16x8 ar[4][2];
  f16x8 br[2][2];

#define STAGE_HALF(t, ab, h) do { \
    const unsigned short* G_ = (ab) ? Bp : Ap; \
    const int rb_ = ((ab) ? bn : bm)*256 + (h)*128; \
    const int k0_ = (t)*64; \
    const int db_ = ((t)&1)*32768 + (ab)*16384 + (h)*8192; \
    _Pragma("unroll") \
    for (int is_=0; is_<2; ++is_){ \
      const int cw_ = wv*64 + is_*512; \
      const int cl_ = cw_ + lane; \
      const int cs_ = cl_ ^ ((cl_>>3)&7); \
      gload16(G_ + (size_t)(rb_ + (cs_>>3))*DI + k0_ + (cs_&7)*8, \
              (unsigned short*)lds + db_ + cw_*8); \
    } } while(0)

#define LD_A(buf, mh) do { \
    const int ba_ = (buf)*32768 + (mh)*8192; \
    _Pragma("unroll") \
    for (int mf_=0; mf_<4; ++mf_) \
    _Pragma("unroll") \
    for (int ks_=0; ks_<2; ++ks_){ \
      const int lin_ = (wm*64 + mf_*16 + fr)*128 + (ks_*4 + fq)*16; \
      const int sz_  = lin_ ^ ((((lin_>>7)&7))<<4); \
      ar[mf_][ks_] = *(const f16x8*)&lds[ba_ + (sz_>>1)]; \
    } } while(0)

#define LD_B(buf, nh) do { \
    const int bb_ = (buf)*32768 + 16384 + (nh)*8192; \
    _Pragma("unroll") \
    for (int nf_=0; nf_<2; ++nf_) \
    _Pragma("unroll") \
    for (int ks_=0; ks_<2; ++ks_){ \
      const int lin_ = (wn*32 + nf_*16 + fr)*128 + (ks_*4 + fq)*16; \
      const int sz_  = lin_ ^ ((((lin_>>7)&7))<<4); \
      br[nf_][ks_] = *(const f16x8*)&lds[bb_ + (sz_>>1)]; \
    } } while(0)

#define MM(mh, nh) do { \
    _Pragma("unroll") \
    for (int mf_=0; mf_<4; ++mf_) \
    _Pragma("unroll") \
    for (int nf_=0; nf_<2; ++nf_) \
    _Pragma("unroll") \
    for (int ks_=0; ks_<2; ++ks_) \
      acc[(mh)*4+mf_][(nh)*2+nf_] = __builtin_amdgcn_mfma_f32_16x16x32_f16( \
          ar[mf_][ks_], br[nf_][ks_], acc[(mh)*4+mf_][(nh)*2+nf_], 0, 0, 0); \
  } while(0)

#define VM6 asm volatile("s_waitcnt vmcnt(6)" ::: "memory")
#define VM0 asm volatile("s_waitcnt vmcnt(0)" ::: "memory")

#define PH(buf, mh, nh, LA_, LB_, STG, VM) do { \
    if (LA_) LD_A(buf, mh); \
    if (LB_) LD_B(buf, nh); \
    STG; \
    VM; \
    __builtin_amdgcn_s_barrier(); \
    asm volatile("s_waitcnt lgkmcnt(0)" ::: "memory"); \
    __builtin_amdgcn_sched_barrier(0); \
    __builtin_amdgcn_s_setprio(1); \
    MM(mh, nh); \
    __builtin_amdgcn_s_setprio(0); \
  } while(0)

  STAGE_HALF(0,0,0); STAGE_HALF(0,1,1); STAGE_HALF(0,0,1); STAGE_HALF(0,1,0);
  STAGE_HALF(1,0,0); STAGE_HALF(1,1,1); STAGE_HALF(1,0,1);
  asm volatile("s_waitcnt vmcnt(6)" ::: "memory");
  __builtin_amdgcn_s_barrier();

  for (int j = 0; j < 15; ++j) {
    const int a = 2*j, b = 2*j+1;
    PH(0, 0,0, 1,1, STAGE_HALF(b,  1,0), (void)0);
    PH(0, 0,1, 0,1, STAGE_HALF(a+2,0,0), (void)0);
    PH(0, 1,1, 1,0, STAGE_HALF(a+2,1,1), (void)0);
    PH(0, 1,0, 0,1, STAGE_HALF(a+2,0,1), VM6);
    PH(1, 0,0, 1,1, STAGE_HALF(a+2,1,0), (void)0);
    PH(1, 0,1, 0,1, STAGE_HALF(b+2,0,0), (void)0);
    PH(1, 1,1, 1,0, STAGE_HALF(b+2,1,1), (void)0);
    PH(1, 1,0, 0,1, STAGE_HALF(b+2,0,1), VM6);
  }
  PH(0, 0,0, 1,1, STAGE_HALF(31,1,0), (void)0);
  PH(0, 0,1, 0,1, (void)0, (void)0);
  PH(0, 1,1, 1,0, (void)0, (void)0);
  PH(0, 1,0, 0,1, (void)0, VM0);
  PH(1, 0,0, 1,1, (void)0, (void)0);
  PH(1, 0,1, 0,1, (void)0, (void)0);
  PH(1, 1,1, 1,0, (void)0, (void)0);
  PH(1, 1,0, 0,1, (void)0, (void)0);

#undef PH
#undef VM6
#undef VM0
#undef MM
#undef LD_B
#undef LD_A
#undef STAGE_HALF

  // direct-store epilogue (R8/R9-proven)
#pragma unroll
  for (int nh=0; nh<2; ++nh)
#pragma unroll
  for (int nf=0; nf<2; ++nf){
    const int col = bn*256 + nh*128 + wn*32 + nf*16 + fr;
    float bs = bias1[col];
    if (HASB2) bs += bias2[col];
#pragma unroll
    for (int mh=0; mh<2; ++mh)
#pragma unroll
    for (int mf=0; mf<4; ++mf){
      const int row0 = bm*256 + mh*128 + wm*64 + mf*16 + fq*4;
#pragma unroll
      for (int q=0; q<4; ++q){
        float v = acc[mh*4+mf][nh*2+nf][q] + bs;
        if (F16OUT) ((unsigned short*)Cout)[(size_t)(row0+q)*N + col] = f2h_bits(v);
        else        ((float*)Cout)[(size_t)(row0+q)*N + col] = v;
      }
    }
  }
}

__global__ __launch_bounds__(512, 2) void k_gemm_enc8(
    const unsigned short* __restrict__ Ap, const unsigned short* __restrict__ Bp,
    const float* __restrict__ bias, unsigned short* __restrict__ C)
{
  gemm8_body<true, false>(Ap, Bp, bias, nullptr, (void*)C, DH);
}

__global__ __launch_bounds__(512, 2) void k_gemm_skip8(
    const unsigned short* __restrict__ Ap, const unsigned short* __restrict__ Bp,
    const float* __restrict__ bias1, const float* __restrict__ bias2,
    float* __restrict__ C)
{
  gemm8_body<false, true>(Ap, Bp, bias1, bias2, (void*)C, DO);
}

// ---------------- exact top-64 per row ----------------
// R17: hist copies 8 -> 16 (lane&15), stride 257 kept (copy c, bucket b ->
// bank (c+b)%32). Halves hot-bucket atomic serialization depth. Everything
// else byte-identical to the R12/R14-proven version.
__global__ __launch_bounds__(256) void k_topk(
    const unsigned short* __restrict__ P,
    const float* __restrict__ X,
    const float* __restrict__ Wenc,
    const float* __restrict__ benc,
    int*   __restrict__ candIdx,
    float* __restrict__ candVal)
{
  __shared__ unsigned int hist16[16][257];   // padded stride
  __shared__ unsigned int hist2[257];
  __shared__ int   inIdx[64];
  __shared__ float inVal[64];
  __shared__ int    bandIdx[BCAP];
  __shared__ double bandVal[BCAP];
  __shared__ int s_inCnt, s_bandCnt, s_sel, s_above, s_sel2;

  const int r = blockIdx.x;
  const int tid = threadIdx.x;
  const int wv = tid >> 6, lane = tid & 63;
  const int lc = lane & 15;
  const unsigned short* Prow = P + (size_t)r*DH;

#pragma unroll
  for (int k=0;k<16;k++) hist16[k][tid] = 0;
  hist2[tid] = 0;
  if (tid==0){ s_inCnt=0; s_bandCnt=0; }

  // row -> 8 named registers (32 VGPR)
  const usx8* Pv = (const usx8*)Prow;
  usx8 c0 = Pv[tid];        usx8 c1 = Pv[tid+256];
  usx8 c2 = Pv[tid+512];    usx8 c3 = Pv[tid+768];
  usx8 c4 = Pv[tid+1024];   usx8 c5 = Pv[tid+1280];
  usx8 c6 = Pv[tid+1536];   usx8 c7 = Pv[tid+1792];
  __syncthreads();

#define OMAP(b) (unsigned short)(((b) & 0x8000) ? (unsigned short)~(b) : (unsigned short)((b)|0x8000))
#define H1(CC) { _Pragma("unroll") for (int e=0;e<8;e++){ \
    unsigned short o = OMAP(CC[e]); atomicAdd(&hist16[lc][o>>8], 1u); } }
  H1(c0) H1(c1) H1(c2) H1(c3) H1(c4) H1(c5) H1(c6) H1(c7)
#undef H1
  __syncthreads();
  {
    unsigned int hs = 0;
#pragma unroll
    for (int c=0;c<16;c++) hs += hist16[c][tid];
    hist16[0][tid] = hs;
  }
  __syncthreads();

  if (tid < 64) {
    const int h0 = 255 - 4*tid;
    unsigned int c0_=hist16[0][h0], c1_=hist16[0][h0-1], c2_=hist16[0][h0-2], c3_=hist16[0][h0-3];
    unsigned int s = c0_+c1_+c2_+c3_;
    unsigned int Pi = s;
#pragma unroll
    for (int off=1; off<64; off<<=1){
      unsigned int t = __shfl_up(Pi, off);
      if (tid >= off) Pi += t;
    }
    unsigned long long mk = __ballot(Pi >= KSEL);
    int cr = (int)__builtin_ctzll(mk);
    if (tid == cr){
      unsigned int cum = Pi - s;
      unsigned int cc[4] = {c0_,c1_,c2_,c3_};
#pragma unroll
      for (int j=0;j<4;j++){
        if (cum + cc[j] >= KSEL){ s_sel = h0-j; s_above = (int)cum; break; }
        cum += cc[j];
      }
    }
  }
  __syncthreads();
  const int bsel = s_sel; const int cntAbove = s_above;

#define H2(CC) { _Pragma("unroll") for (int e=0;e<8;e++){ \
    unsigned short o = OMAP(CC[e]); \
    if ((int)(o>>8) == bsel) atomicAdd(&hist2[o & 0xff], 1u); } }
  H2(c0) H2(c1) H2(c2) H2(c3) H2(c4) H2(c5) H2(c6) H2(c7)
#undef H2
  __syncthreads();
  {
    const int K2 = KSEL - cntAbove;
    if (tid < 64) {
      const int h0 = 255 - 4*tid;
      unsigned int c0_=hist2[h0], c1_=hist2[h0-1], c2_=hist2[h0-2], c3_=hist2[h0-3];
      unsigned int s = c0_+c1_+c2_+c3_;
      unsigned int Pi = s;
#pragma unroll
      for (int off=1; off<64; off<<=1){
        unsigned int t = __shfl_up(Pi, off);
        if (tid >= off) Pi += t;
      }
      unsigned long long mk = __ballot(Pi >= (unsigned)K2);
      int cr = (int)__builtin_ctzll(mk);
      if (tid == cr){
        unsigned int cum = Pi - s;
        unsigned int cc[4] = {c0_,c1_,c2_,c3_};
#pragma unroll
        for (int j=0;j<4;j++){
          if (cum + cc[j] >= (unsigned)K2){ s_sel2 = h0-j; break; }
          cum += cc[j];
        }
      }
    }
  }
  __syncthreads();

  unsigned short To = (unsigned short)((bsel<<8) | s_sel2);
  unsigned short tb = (To & 0x8000) ? (unsigned short)(To ^ 0x8000) : (unsigned short)~To;
  const float T = h_bits2f(tb);
  const float hiv = T + 2.0f*EPS_SEL, lov = T - 2.0f*EPS_SEL;

#define EXT(CC, KK) { _Pragma("unroll") for (int e=0;e<8;e++){ \
    float v = h_bits2f(CC[e]); \
    if (v > hiv){ \
      int p = atomicAdd(&s_inCnt,1); \
      if (p < 64){ inIdx[p] = (tid + (KK)*256)*8 + e; inVal[p] = v; } \
    } else if (v >= lov){ \
      int p = atomicAdd(&s_bandCnt,1); \
      if (p < BCAP) bandIdx[p] = (tid + (KK)*256)*8 + e; \
    } } }
  EXT(c0,0) EXT(c1,1) EXT(c2,2) EXT(c3,3) EXT(c4,4) EXT(c5,5) EXT(c6,6) EXT(c7,7)
#undef EXT
#undef OMAP
  __syncthreads();
  const int m = s_inCnt < 64 ? s_inCnt : 64;
  const int B = s_bandCnt < BCAP ? s_bandCnt : BCAP;

  // exact f64 recompute for ambiguous band (4-way ILP partial sums)
  const float* Xr = X + (size_t)r*DI;
  for (int b=wv; b<B; b+=4){
    const int j = bandIdx[b];
    const float* Wr = Wenc + (size_t)j*DI;
    double s0=0.0, s1=0.0, s2=0.0, s3=0.0;
    for (int k0=lane; k0<DI; k0+=256){
      s0 = fma((double)Xr[k0],     (double)Wr[k0],     s0);
      s1 = fma((double)Xr[k0+64],  (double)Wr[k0+64],  s1);
      s2 = fma((double)Xr[k0+128], (double)Wr[k0+128], s2);
      s3 = fma((double)Xr[k0+192], (double)Wr[k0+192], s3);
    }
    double s = (s0+s1)+(s2+s3);
#pragma unroll
    for (int off=32; off>=1; off>>=1) s += __shfl_down(s, off);
    if (lane==0) bandVal[b] = s + (double)benc[j];
  }
  __syncthreads();

  int* ci = candIdx + (size_t)r*KSEL;
  float* cv = candVal + (size_t)r*KSEL;
  for (int t=tid; t<m; t+=256){ ci[t]=inIdx[t]; cv[t]=inVal[t]; }

  const int need = KSEL - m;
  if (tid < 64 && need > 0){
    unsigned int used = 0;
    for (int t=0;t<need;t++){
      double best = -1.0e300; int bi = -1;
#pragma unroll
      for (int sIt=0;sIt<4;sIt++){
        int b = tid + sIt*64;
        if (b < B && !((used>>sIt)&1)){
          double v = bandVal[b];
          if (v > best){ best=v; bi=b; }
        }
      }
#pragma unroll
      for (int off=32; off>=1; off>>=1){
        double ov = __shfl_down(best, off);
        int    oi = __shfl_down(bi,   off);
        if (ov > best){ best = ov; bi = oi; }
      }
      bi   = __shfl(bi, 0);
      best = __shfl(best, 0);
      if ((bi & 63) == tid) used |= 1u << (bi >> 6);
      if (tid == 0){
        ci[m+t] = bandIdx[bi];
        cv[m+t] = (float)best;
      }
    }
  }
}

// ---------------- sparse decode (fp8 gather) + loss partial ----------------
__global__ __launch_bounds__(256) void k_decode(
    float* __restrict__ outhat,
    const unsigned char* __restrict__ WdT8,
    const int*   __restrict__ candIdx,
    const float* __restrict__ candVal,
    const float* __restrict__ target,
    float* __restrict__ lossPartial)
{
  __shared__ int   sIdx[KSEL];
  __shared__ float sVal[KSEL];
  __shared__ float wsum[4];
  const int r = blockIdx.x, tid = threadIdx.x;
  if (tid < KSEL){
    sIdx[tid]=candIdx[(size_t)r*KSEL+tid];
    float v=candVal[(size_t)r*KSEL+tid];
    sVal[tid] = (v>0.f ? v : 0.f) * 0.015625f;   // /64 descale
  }
  __syncthreads();
  float* orow = outhat + (size_t)r*DO;
  float a[8];
  {
    float4 v0 = *(const float4*)(orow + tid*8);
    float4 v1 = *(const float4*)(orow + tid*8 + 4);
    a[0]=v0.x;a[1]=v0.y;a[2]=v0.z;a[3]=v0.w;a[4]=v1.x;a[5]=v1.y;a[6]=v1.z;a[7]=v1.w;
  }
#pragma unroll 4
  for (int c=0;c<KSEL;c++){
    const float v = sVal[c];
    const uint2 w = *(const uint2*)(WdT8 + (size_t)sIdx[c]*DO + tid*8);
    a[0] = fmaf(v, __builtin_amdgcn_cvt_f32_fp8(w.x, 0), a[0]);
    a[1] = fmaf(v, __builtin_amdgcn_cvt_f32_fp8(w.x, 1), a[1]);
    a[2] = fmaf(v, __builtin_amdgcn_cvt_f32_fp8(w.x, 2), a[2]);
    a[3] = fmaf(v, __builtin_amdgcn_cvt_f32_fp8(w.x, 3), a[3]);
    a[4] = fmaf(v, __builtin_amdgcn_cvt_f32_fp8(w.y, 0), a[4]);
    a[5] = fmaf(v, __builtin_amdgcn_cvt_f32_fp8(w.y, 1), a[5]);
    a[6] = fmaf(v, __builtin_amdgcn_cvt_f32_fp8(w.y, 2), a[6]);
    a[7] = fmaf(v, __builtin_amdgcn_cvt_f32_fp8(w.y, 3), a[7]);
  }
  const float* trow = target + (size_t)r*DO;
  float4 t0 = *(const float4*)(trow + tid*8);
  float4 t1 = *(const float4*)(trow + tid*8 + 4);
  float tt[8] = {t0.x,t0.y,t0.z,t0.w,t1.x,t1.y,t1.z,t1.w};
  float ls = 0.f;
#pragma unroll
  for (int j=0;j<8;j++){ float d = a[j]-tt[j]; ls = fmaf(d,d,ls); }
  {
    float4 v0 = {a[0],a[1],a[2],a[3]}, v1 = {a[4],a[5],a[6],a[7]};
    *(float4*)(orow + tid*8) = v0;
    *(float4*)(orow + tid*8 + 4) = v1;
  }
#pragma unroll
  for (int off=32; off>=1; off>>=1) ls += __shfl_down(ls, off);
  if ((tid&63)==0) wsum[tid>>6]=ls;
  __syncthreads();
  if (tid==0)
    lossPartial[r] = (wsum[0]+wsum[1]+wsum[2]+wsum[3]) * (1.0f/((float)NT*(float)DO));
}

__global__ __launch_bounds__(256) void k_lossreduce(const float* __restrict__ lp,
                                                    float* __restrict__ out)
{
  __shared__ double ws[4];
  double s=0.0;
  for (int i=threadIdx.x;i<NT;i+=256) s += (double)lp[i];
#pragma unroll
  for (int off=32; off>=1; off>>=1) s += __shfl_down(s, off);
  if ((threadIdx.x&63)==0) ws[threadIdx.x>>6]=s;
  __syncthreads();
  if (threadIdx.x==0) *out = (float)(ws[0]+ws[1]+ws[2]+ws[3]);
}

// ---------------- finalize h: zero + scatter ----------------
__global__ __launch_bounds__(256) void k_scatter(
    float* __restrict__ H, const int* __restrict__ candIdx, const float* __restrict__ candVal)
{
  const int r=blockIdx.x, tid=threadIdx.x;
  float* hr = H + (size_t)r*DH;
  const float4 z = {0.f,0.f,0.f,0.f};
#pragma unroll
  for (int i=0;i<16;i++) ((float4*)hr)[tid + i*256] = z;
  __syncthreads();
  if (tid<KSEL){
    float v = candVal[(size_t)r*KSEL+tid];
    hr[candIdx[(size_t)r*KSEL+tid]] = v>0.f ? v : 0.f;
  }
}

extern "C" void kernel_launch(void* const* d_in, const int* in_sizes, int n_in,
                              void* d_out, int out_size, void* d_ws, size_t ws_size,
                              hipStream_t stream)
{
  const float* X     = (const float*)d_in[0];
  const float* tgt   = (const float*)d_in[1];
  const float* Wenc  = (const float*)d_in[2];
  const float* benc  = (const float*)d_in[3];
  const float* Wdec  = (const float*)d_in[4];
  const float* bdec  = (const float*)d_in[5];
  const float* Wskip = (const float*)d_in[6];
  const float* bskip = (const float*)d_in[7];

  float* out     = (float*)d_out;
  float* outhat  = out;
  float* H       = out + (size_t)NT*DO;
  float* lossOut = out + (size_t)NT*DO + (size_t)NT*DH;

  // h-region scratch plan (dead until k_scatter)
  char* hb = (char*)H;
  unsigned short* P      = (unsigned short*)hb;
  char* U                = hb + (size_t)NT*DH*2;
  unsigned short* Xh     = (unsigned short*)U;
  unsigned short* Wench  = (unsigned short*)(U + (size_t)NT*DI*2);
  unsigned short* Wskiph = (unsigned short*)(U + (size_t)NT*DI*2 + (size_t)DH*DI*2);
  unsigned char*  WdT8   = (unsigned char*)(U + (size_t)NT*DI*2 + (size_t)DH*DI*2 + (size_t)DO*DI*2);

  int*   candIdx    = (int*)d_ws;
  float* candVal    = (float*)((char*)d_ws + (size_t)NT*KSEL*4);
  float* lossPartial= (float*)((char*)d_ws + (size_t)NT*KSEL*8);

  k_cvt<<<NT*DI/8/256, 256, 0, stream>>>(X, Xh, NT*DI/8);
  k_cvt<<<DH*DI/8/256, 256, 0, stream>>>(Wenc, Wench, DH*DI/8);
  k_cvt<<<DO*DI/8/256, 256, 0, stream>>>(Wskip, Wskiph, DO*DI/8);
  k_transpose_cvt8<<<dim3(DO/64, DH/64), 256, 0, stream>>>(Wdec, WdT8);

  k_gemm_enc8<<<dim3(NT/256, DH/256), 512, 0, stream>>>(Xh, Wench, benc, P);
  k_topk<<<NT, 256, 0, stream>>>(P, X, Wenc, benc, candIdx, candVal);
  k_gemm_skip8<<<dim3(NT/256, DO/256), 512, 0, stream>>>(Xh, Wskiph, bdec, bskip, outhat);
  k_decode<<<NT, 256, 0, stream>>>(outhat, WdT8, candIdx, candVal, tgt, lossPartial);
  k_lossreduce<<<1, 256, 0, stream>>>(lossPartial, lossOut);
  k_scatter<<<NT, 256, 0, stream>>>(H, candIdx, candVal);
}

// Round 19
// 1146.554 us; speedup vs baseline: 1.8581x; 1.0046x over previous
//
#include <hip/hip_runtime.h>
#include <stdint.h>

#define NT   8192
#define DI   2048
#define DH   16384
#define DO   2048
#define KSEL 64
#define EPS_SEL 0.004f
#define BCAP 256
// h rows physically hosting WdT8 (byte range [360MB, 392MB) of the h region)
#define WDT_ROW_LO 5760
#define WDT_ROW_HI 6272

typedef _Float16 f16;
typedef f16  f16x8 __attribute__((ext_vector_type(8)));
typedef float f32x4 __attribute__((ext_vector_type(4)));
typedef unsigned short usx8 __attribute__((ext_vector_type(8)));

__device__ __forceinline__ unsigned short f2h_bits(float x){
  f16 h = (f16)x;
  union { f16 h; unsigned short u; } c; c.h = h; return c.u;
}
__device__ __forceinline__ float h_bits2f(unsigned short u){
  union { unsigned short u; f16 h; } c; c.u = u; return (float)c.h;
}
__device__ __forceinline__ unsigned char f2fp8(float x){
  return (unsigned char)(__builtin_amdgcn_cvt_pk_fp8_f32(x, 0.f, 0u, false) & 0xff);
}

__device__ __forceinline__ void gload16(const void* g, void* lds){
  __builtin_amdgcn_global_load_lds(
    (const __attribute__((address_space(1))) void*)(uintptr_t)g,
    (__attribute__((address_space(3))) void*)(uint32_t)(uintptr_t)lds,
    16, 0, 0);
}

// ---------------- f32 -> f16 convert (vector8) ----------------
__global__ __launch_bounds__(256) void k_cvt(const float* __restrict__ in,
                                             unsigned short* __restrict__ out, int n8)
{
  int i = blockIdx.x*256 + threadIdx.x;
  if (i >= n8) return;
  const float4* p = (const float4*)in + (size_t)i*2;
  float4 a = p[0], b = p[1];
  union { f16 h[8]; usx8 u; } r;
  r.h[0]=(f16)a.x; r.h[1]=(f16)a.y; r.h[2]=(f16)a.z; r.h[3]=(f16)a.w;
  r.h[4]=(f16)b.x; r.h[5]=(f16)b.y; r.h[6]=(f16)b.z; r.h[7]=(f16)b.w;
  ((usx8*)out)[i] = r.u;
}

// -------- W_dec [DO][DH] f32 -> WdecT8 [DH][DO] fp8 e4m3, pre-scaled x64 -----
__global__ __launch_bounds__(256) void k_transpose_cvt8(const float* __restrict__ W,
                                                        unsigned char* __restrict__ WT)
{
  __shared__ unsigned char t[64][68];
  const int r0 = blockIdx.x*64;   // over DO
  const int c0 = blockIdx.y*64;   // over DH
  const int tid = threadIdx.x;
  const int q = tid >> 6, s = tid & 63;
#pragma unroll
  for (int i=0;i<16;i++){
    int r = q + i*4;
    t[r][s] = f2fp8(W[(size_t)(r0+r)*DH + c0 + s] * 64.0f);
  }
  __syncthreads();
#pragma unroll
  for (int i=0;i<16;i++){
    int c = q + i*4;
    WT[(size_t)(c0+c)*DO + r0 + s] = t[s][c];
  }
}

// ============ 256^2 8-phase GEMM template (R14-proven) ============
template<bool F16OUT, bool HASB2>
__device__ __forceinline__ void gemm8_body(
    const unsigned short* __restrict__ Ap,
    const unsigned short* __restrict__ Bp,
    const float* __restrict__ bias1,
    const float* __restrict__ bias2,
    void* __restrict__ Cout, int N)
{
  __shared__ unsigned short lds[65536];   // 128 KB
  const int tid  = threadIdx.x;
  const int lane = tid & 63;
  const int wv   = tid >> 6;
  const int wm   = wv >> 2;     // 0..1
  const int wn   = wv & 3;      // 0..3
  const int bm   = blockIdx.x;  // fastest -> B-panel reuse (R5-proven)
  const int bn   = blockIdx.y;
  const int fr   = lane & 15;
  const int fq   = lane >> 4;

  f32x4 acc[8][4];
#pragma unroll
  for (int i=0;i<8;i++)
#pragma unroll
    for (int j=0;j<4;j++) acc[i][j] = (f32x4){0.f,0.f,0.f,0.f};

  f16x8 ar[4][2];
  f16x8 br[2][2];

#define STAGE_HALF(t, ab, h) do { \
    const unsigned short* G_ = (ab) ? Bp : Ap; \
    const int rb_ = ((ab) ? bn : bm)*256 + (h)*128; \
    const int k0_ = (t)*64; \
    const int db_ = ((t)&1)*32768 + (ab)*16384 + (h)*8192; \
    _Pragma("unroll") \
    for (int is_=0; is_<2; ++is_){ \
      const int cw_ = wv*64 + is_*512; \
      const int cl_ = cw_ + lane; \
      const int cs_ = cl_ ^ ((cl_>>3)&7); \
      gload16(G_ + (size_t)(rb_ + (cs_>>3))*DI + k0_ + (cs_&7)*8, \
              (unsigned short*)lds + db_ + cw_*8); \
    } } while(0)

#define LD_A(buf, mh) do { \
    const int ba_ = (buf)*32768 + (mh)*8192; \
    _Pragma("unroll") \
    for (int mf_=0; mf_<4; ++mf_) \
    _Pragma("unroll") \
    for (int ks_=0; ks_<2; ++ks_){ \
      const int lin_ = (wm*64 + mf_*16 + fr)*128 + (ks_*4 + fq)*16; \
      const int sz_  = lin_ ^ ((((lin_>>7)&7))<<4); \
      ar[mf_][ks_] = *(const f16x8*)&lds[ba_ + (sz_>>1)]; \
    } } while(0)

#define LD_B(buf, nh) do { \
    const int bb_ = (buf)*32768 + 16384 + (nh)*8192; \
    _Pragma("unroll") \
    for (int nf_=0; nf_<2; ++nf_) \
    _Pragma("unroll") \
    for (int ks_=0; ks_<2; ++ks_){ \
      const int lin_ = (wn*32 + nf_*16 + fr)*128 + (ks_*4 + fq)*16; \
      const int sz_  = lin_ ^ ((((lin_>>7)&7))<<4); \
      br[nf_][ks_] = *(const f16x8*)&lds[bb_ + (sz_>>1)]; \
    } } while(0)

#define MM(mh, nh) do { \
    _Pragma("unroll") \
    for (int mf_=0; mf_<4; ++mf_) \
    _Pragma("unroll") \
    for (int nf_=0; nf_<2; ++nf_) \
    _Pragma("unroll") \
    for (int ks_=0; ks_<2; ++ks_) \
      acc[(mh)*4+mf_][(nh)*2+nf_] = __builtin_amdgcn_mfma_f32_16x16x32_f16( \
          ar[mf_][ks_], br[nf_][ks_], acc[(mh)*4+mf_][(nh)*2+nf_], 0, 0, 0); \
  } while(0)

#define VM6 asm volatile("s_waitcnt vmcnt(6)" ::: "memory")
#define VM0 asm volatile("s_waitcnt vmcnt(0)" ::: "memory")

#define PH(buf, mh, nh, LA_, LB_, STG, VM) do { \
    if (LA_) LD_A(buf, mh); \
    if (LB_) LD_B(buf, nh); \
    STG; \
    VM; \
    __builtin_amdgcn_s_barrier(); \
    asm volatile("s_waitcnt lgkmcnt(0)" ::: "memory"); \
    __builtin_amdgcn_sched_barrier(0); \
    __builtin_amdgcn_s_setprio(1); \
    MM(mh, nh); \
    __builtin_amdgcn_s_setprio(0); \
  } while(0)

  STAGE_HALF(0,0,0); STAGE_HALF(0,1,1); STAGE_HALF(0,0,1); STAGE_HALF(0,1,0);
  STAGE_HALF(1,0,0); STAGE_HALF(1,1,1); STAGE_HALF(1,0,1);
  asm volatile("s_waitcnt vmcnt(6)" ::: "memory");
  __builtin_amdgcn_s_barrier();

  for (int j = 0; j < 15; ++j) {
    const int a = 2*j, b = 2*j+1;
    PH(0, 0,0, 1,1, STAGE_HALF(b,  1,0), (void)0);
    PH(0, 0,1, 0,1, STAGE_HALF(a+2,0,0), (void)0);
    PH(0, 1,1, 1,0, STAGE_HALF(a+2,1,1), (void)0);
    PH(0, 1,0, 0,1, STAGE_HALF(a+2,0,1), VM6);
    PH(1, 0,0, 1,1, STAGE_HALF(a+2,1,0), (void)0);
    PH(1, 0,1, 0,1, STAGE_HALF(b+2,0,0), (void)0);
    PH(1, 1,1, 1,0, STAGE_HALF(b+2,1,1), (void)0);
    PH(1, 1,0, 0,1, STAGE_HALF(b+2,0,1), VM6);
  }
  PH(0, 0,0, 1,1, STAGE_HALF(31,1,0), (void)0);
  PH(0, 0,1, 0,1, (void)0, (void)0);
  PH(0, 1,1, 1,0, (void)0, (void)0);
  PH(0, 1,0, 0,1, (void)0, VM0);
  PH(1, 0,0, 1,1, (void)0, (void)0);
  PH(1, 0,1, 0,1, (void)0, (void)0);
  PH(1, 1,1, 1,0, (void)0, (void)0);
  PH(1, 1,0, 0,1, (void)0, (void)0);

#undef PH
#undef VM6
#undef VM0
#undef MM
#undef LD_B
#undef LD_A
#undef STAGE_HALF

  // direct-store epilogue (R8/R9-proven)
#pragma unroll
  for (int nh=0; nh<2; ++nh)
#pragma unroll
  for (int nf=0; nf<2; ++nf){
    const int col = bn*256 + nh*128 + wn*32 + nf*16 + fr;
    float bs = bias1[col];
    if (HASB2) bs += bias2[col];
#pragma unroll
    for (int mh=0; mh<2; ++mh)
#pragma unroll
    for (int mf=0; mf<4; ++mf){
      const int row0 = bm*256 + mh*128 + wm*64 + mf*16 + fq*4;
#pragma unroll
      for (int q=0; q<4; ++q){
        float v = acc[mh*4+mf][nh*2+nf][q] + bs;
        if (F16OUT) ((unsigned short*)Cout)[(size_t)(row0+q)*N + col] = f2h_bits(v);
        else        ((float*)Cout)[(size_t)(row0+q)*N + col] = v;
      }
    }
  }
}

__global__ __launch_bounds__(512, 2) void k_gemm_enc8(
    const unsigned short* __restrict__ Ap, const unsigned short* __restrict__ Bp,
    const float* __restrict__ bias, unsigned short* __restrict__ C)
{
  gemm8_body<true, false>(Ap, Bp, bias, nullptr, (void*)C, DH);
}

__global__ __launch_bounds__(512, 2) void k_gemm_skip8(
    const unsigned short* __restrict__ Ap, const unsigned short* __restrict__ Bp,
    const float* __restrict__ bias1, const float* __restrict__ bias2,
    float* __restrict__ C)
{
  gemm8_body<false, true>(Ap, Bp, bias1, bias2, (void*)C, DO);
}

// ---------------- exact top-64 per row (R17 body; measured == R14) ----------
__global__ __launch_bounds__(256) void k_topk(
    const unsigned short* __restrict__ P,
    const float* __restrict__ X,
    const float* __restrict__ Wenc,
    const float* __restrict__ benc,
    int*   __restrict__ candIdx,
    float* __restrict__ candVal)
{
  __shared__ unsigned int hist16[16][257];
  __shared__ unsigned int hist2[257];
  __shared__ int   inIdx[64];
  __shared__ float inVal[64];
  __shared__ int    bandIdx[BCAP];
  __shared__ double bandVal[BCAP];
  __shared__ int s_inCnt, s_bandCnt, s_sel, s_above, s_sel2;

  const int r = blockIdx.x;
  const int tid = threadIdx.x;
  const int wv = tid >> 6, lane = tid & 63;
  const int lc = lane & 15;
  const unsigned short* Prow = P + (size_t)r*DH;

#pragma unroll
  for (int k=0;k<16;k++) hist16[k][tid] = 0;
  hist2[tid] = 0;
  if (tid==0){ s_inCnt=0; s_bandCnt=0; }

  const usx8* Pv = (const usx8*)Prow;
  usx8 c0 = Pv[tid];        usx8 c1 = Pv[tid+256];
  usx8 c2 = Pv[tid+512];    usx8 c3 = Pv[tid+768];
  usx8 c4 = Pv[tid+1024];   usx8 c5 = Pv[tid+1280];
  usx8 c6 = Pv[tid+1536];   usx8 c7 = Pv[tid+1792];
  __syncthreads();

#define OMAP(b) (unsigned short)(((b) & 0x8000) ? (unsigned short)~(b) : (unsigned short)((b)|0x8000))
#define H1(CC) { _Pragma("unroll") for (int e=0;e<8;e++){ \
    unsigned short o = OMAP(CC[e]); atomicAdd(&hist16[lc][o>>8], 1u); } }
  H1(c0) H1(c1) H1(c2) H1(c3) H1(c4) H1(c5) H1(c6) H1(c7)
#undef H1
  __syncthreads();
  {
    unsigned int hs = 0;
#pragma unroll
    for (int c=0;c<16;c++) hs += hist16[c][tid];
    hist16[0][tid] = hs;
  }
  __syncthreads();

  if (tid < 64) {
    const int h0 = 255 - 4*tid;
    unsigned int c0_=hist16[0][h0], c1_=hist16[0][h0-1], c2_=hist16[0][h0-2], c3_=hist16[0][h0-3];
    unsigned int s = c0_+c1_+c2_+c3_;
    unsigned int Pi = s;
#pragma unroll
    for (int off=1; off<64; off<<=1){
      unsigned int t = __shfl_up(Pi, off);
      if (tid >= off) Pi += t;
    }
    unsigned long long mk = __ballot(Pi >= KSEL);
    int cr = (int)__builtin_ctzll(mk);
    if (tid == cr){
      unsigned int cum = Pi - s;
      unsigned int cc[4] = {c0_,c1_,c2_,c3_};
#pragma unroll
      for (int j=0;j<4;j++){
        if (cum + cc[j] >= KSEL){ s_sel = h0-j; s_above = (int)cum; break; }
        cum += cc[j];
      }
    }
  }
  __syncthreads();
  const int bsel = s_sel; const int cntAbove = s_above;

#define H2(CC) { _Pragma("unroll") for (int e=0;e<8;e++){ \
    unsigned short o = OMAP(CC[e]); \
    if ((int)(o>>8) == bsel) atomicAdd(&hist2[o & 0xff], 1u); } }
  H2(c0) H2(c1) H2(c2) H2(c3) H2(c4) H2(c5) H2(c6) H2(c7)
#undef H2
  __syncthreads();
  {
    const int K2 = KSEL - cntAbove;
    if (tid < 64) {
      const int h0 = 255 - 4*tid;
      unsigned int c0_=hist2[h0], c1_=hist2[h0-1], c2_=hist2[h0-2], c3_=hist2[h0-3];
      unsigned int s = c0_+c1_+c2_+c3_;
      unsigned int Pi = s;
#pragma unroll
      for (int off=1; off<64; off<<=1){
        unsigned int t = __shfl_up(Pi, off);
        if (tid >= off) Pi += t;
      }
      unsigned long long mk = __ballot(Pi >= (unsigned)K2);
      int cr = (int)__builtin_ctzll(mk);
      if (tid == cr){
        unsigned int cum = Pi - s;
        unsigned int cc[4] = {c0_,c1_,c2_,c3_};
#pragma unroll
        for (int j=0;j<4;j++){
          if (cum + cc[j] >= (unsigned)K2){ s_sel2 = h0-j; break; }
          cum += cc[j];
        }
      }
    }
  }
  __syncthreads();

  unsigned short To = (unsigned short)((bsel<<8) | s_sel2);
  unsigned short tb = (To & 0x8000) ? (unsigned short)(To ^ 0x8000) : (unsigned short)~To;
  const float T = h_bits2f(tb);
  const float hiv = T + 2.0f*EPS_SEL, lov = T - 2.0f*EPS_SEL;

#define EXT(CC, KK) { _Pragma("unroll") for (int e=0;e<8;e++){ \
    float v = h_bits2f(CC[e]); \
    if (v > hiv){ \
      int p = atomicAdd(&s_inCnt,1); \
      if (p < 64){ inIdx[p] = (tid + (KK)*256)*8 + e; inVal[p] = v; } \
    } else if (v >= lov){ \
      int p = atomicAdd(&s_bandCnt,1); \
      if (p < BCAP) bandIdx[p] = (tid + (KK)*256)*8 + e; \
    } } }
  EXT(c0,0) EXT(c1,1) EXT(c2,2) EXT(c3,3) EXT(c4,4) EXT(c5,5) EXT(c6,6) EXT(c7,7)
#undef EXT
#undef OMAP
  __syncthreads();
  const int m = s_inCnt < 64 ? s_inCnt : 64;
  const int B = s_bandCnt < BCAP ? s_bandCnt : BCAP;

  const float* Xr = X + (size_t)r*DI;
  for (int b=wv; b<B; b+=4){
    const int j = bandIdx[b];
    const float* Wr = Wenc + (size_t)j*DI;
    double s0=0.0, s1=0.0, s2=0.0, s3=0.0;
    for (int k0=lane; k0<DI; k0+=256){
      s0 = fma((double)Xr[k0],     (double)Wr[k0],     s0);
      s1 = fma((double)Xr[k0+64],  (double)Wr[k0+64],  s1);
      s2 = fma((double)Xr[k0+128], (double)Wr[k0+128], s2);
      s3 = fma((double)Xr[k0+192], (double)Wr[k0+192], s3);
    }
    double s = (s0+s1)+(s2+s3);
#pragma unroll
    for (int off=32; off>=1; off>>=1) s += __shfl_down(s, off);
    if (lane==0) bandVal[b] = s + (double)benc[j];
  }
  __syncthreads();

  int* ci = candIdx + (size_t)r*KSEL;
  float* cv = candVal + (size_t)r*KSEL;
  for (int t=tid; t<m; t+=256){ ci[t]=inIdx[t]; cv[t]=inVal[t]; }

  const int need = KSEL - m;
  if (tid < 64 && need > 0){
    unsigned int used = 0;
    for (int t=0;t<need;t++){
      double best = -1.0e300; int bi = -1;
#pragma unroll
      for (int sIt=0;sIt<4;sIt++){
        int b = tid + sIt*64;
        if (b < B && !((used>>sIt)&1)){
          double v = bandVal[b];
          if (v > best){ best=v; bi=b; }
        }
      }
#pragma unroll
      for (int off=32; off>=1; off>>=1){
        double ov = __shfl_down(best, off);
        int    oi = __shfl_down(bi,   off);
        if (ov > best){ best = ov; bi = oi; }
      }
      bi   = __shfl(bi, 0);
      best = __shfl(best, 0);
      if ((bi & 63) == tid) used |= 1u << (bi >> 6);
      if (tid == 0){
        ci[m+t] = bandIdx[bi];
        cv[m+t] = (float)best;
      }
    }
  }
}

// ------- merged sparse decode (fp8 gather) + loss partial + h scatter -------
// R18: decode's L3-gather latency overlaps scatter's HBM write stream (different
// pipes). Rows [WDT_ROW_LO, WDT_ROW_HI) physically host WdT8 (still being
// gathered) -> their h scatter is deferred to k_scatter_fix.
__global__ __launch_bounds__(256) void k_decode_scatter(
    float* __restrict__ outhat,
    float* __restrict__ H,
    const unsigned char* __restrict__ WdT8,
    const int*   __restrict__ candIdx,
    const float* __restrict__ candVal,
    const float* __restrict__ target,
    float* __restrict__ lossPartial)
{
  __shared__ int   sIdx[KSEL];
  __shared__ float sVal[KSEL];   // relu'd raw value (for h scatter)
  __shared__ float wsum[4];
  const int r = blockIdx.x, tid = threadIdx.x;
  if (tid < KSEL){
    sIdx[tid]=candIdx[(size_t)r*KSEL+tid];
    float v=candVal[(size_t)r*KSEL+tid];
    sVal[tid] = v>0.f ? v : 0.f;
  }
  const bool doScatter = (r < WDT_ROW_LO) || (r >= WDT_ROW_HI);
  float* hr = H + (size_t)r*DH;
  if (doScatter){
    const float4 z = {0.f,0.f,0.f,0.f};
#pragma unroll
    for (int i=0;i<16;i++) ((float4*)hr)[tid + i*256] = z;
  }
  __syncthreads();
  float* orow = outhat + (size_t)r*DO;
  float a[8];
  {
    float4 v0 = *(const float4*)(orow + tid*8);
    float4 v1 = *(const float4*)(orow + tid*8 + 4);
    a[0]=v0.x;a[1]=v0.y;a[2]=v0.z;a[3]=v0.w;a[4]=v1.x;a[5]=v1.y;a[6]=v1.z;a[7]=v1.w;
  }
#pragma unroll 4
  for (int c=0;c<KSEL;c++){
    const float v = sVal[c] * 0.015625f;   // /64 descale
    const uint2 w = *(const uint2*)(WdT8 + (size_t)sIdx[c]*DO + tid*8);
    a[0] = fmaf(v, __builtin_amdgcn_cvt_f32_fp8(w.x, 0), a[0]);
    a[1] = fmaf(v, __builtin_amdgcn_cvt_f32_fp8(w.x, 1), a[1]);
    a[2] = fmaf(v, __builtin_amdgcn_cvt_f32_fp8(w.x, 2), a[2]);
    a[3] = fmaf(v, __builtin_amdgcn_cvt_f32_fp8(w.x, 3), a[3]);
    a[4] = fmaf(v, __builtin_amdgcn_cvt_f32_fp8(w.y, 0), a[4]);
    a[5] = fmaf(v, __builtin_amdgcn_cvt_f32_fp8(w.y, 1), a[5]);
    a[6] = fmaf(v, __builtin_amdgcn_cvt_f32_fp8(w.y, 2), a[6]);
    a[7] = fmaf(v, __builtin_amdgcn_cvt_f32_fp8(w.y, 3), a[7]);
  }
  const float* trow = target + (size_t)r*DO;
  float4 t0 = *(const float4*)(trow + tid*8);
  float4 t1 = *(const float4*)(trow + tid*8 + 4);
  float tt[8] = {t0.x,t0.y,t0.z,t0.w,t1.x,t1.y,t1.z,t1.w};
  float ls = 0.f;
#pragma unroll
  for (int j=0;j<8;j++){ float d = a[j]-tt[j]; ls = fmaf(d,d,ls); }
  {
    float4 v0 = {a[0],a[1],a[2],a[3]}, v1 = {a[4],a[5],a[6],a[7]};
    *(float4*)(orow + tid*8) = v0;
    *(float4*)(orow + tid*8 + 4) = v1;
  }
#pragma unroll
  for (int off=32; off>=1; off>>=1) ls += __shfl_down(ls, off);
  if ((tid&63)==0) wsum[tid>>6]=ls;
  __syncthreads();
  if (tid==0)
    lossPartial[r] = (wsum[0]+wsum[1]+wsum[2]+wsum[3]) * (1.0f/((float)NT*(float)DO));
  if (doScatter && tid < KSEL)
    hr[sIdx[tid]] = sVal[tid];
}

// ---- deferred scatter for the 512 rows that hosted WdT8 (runs after all
// gathers are complete) ----
__global__ __launch_bounds__(256) void k_scatter_fix(
    float* __restrict__ H, const int* __restrict__ candIdx, const float* __restrict__ candVal)
{
  const int r = WDT_ROW_LO + blockIdx.x, tid = threadIdx.x;
  float* hr = H + (size_t)r*DH;
  const float4 z = {0.f,0.f,0.f,0.f};
#pragma unroll
  for (int i=0;i<16;i++) ((float4*)hr)[tid + i*256] = z;
  __syncthreads();
  if (tid<KSEL){
    float v = candVal[(size_t)r*KSEL+tid];
    hr[candIdx[(size_t)r*KSEL+tid]] = v>0.f ? v : 0.f;
  }
}

__global__ __launch_bounds__(256) void k_lossreduce(const float* __restrict__ lp,
                                                    float* __restrict__ out)
{
  __shared__ double ws[4];
  double s=0.0;
  for (int i=threadIdx.x;i<NT;i+=256) s += (double)lp[i];
#pragma unroll
  for (int off=32; off>=1; off>>=1) s += __shfl_down(s, off);
  if ((threadIdx.x&63)==0) ws[threadIdx.x>>6]=s;
  __syncthreads();
  if (threadIdx.x==0) *out = (float)(ws[0]+ws[1]+ws[2]+ws[3]);
}

extern "C" void kernel_launch(void* const* d_in, const int* in_sizes, int n_in,
                              void* d_out, int out_size, void* d_ws, size_t ws_size,
                              hipStream_t stream)
{
  const float* X     = (const float*)d_in[0];
  const float* tgt   = (const float*)d_in[1];
  const float* Wenc  = (const float*)d_in[2];
  const float* benc  = (const float*)d_in[3];
  const float* Wdec  = (const float*)d_in[4];
  const float* bdec  = (const float*)d_in[5];
  const float* Wskip = (const float*)d_in[6];
  const float* bskip = (const float*)d_in[7];

  float* out     = (float*)d_out;
  float* outhat  = out;
  float* H       = out + (size_t)NT*DO;
  float* lossOut = out + (size_t)NT*DO + (size_t)NT*DH;

  // h-region scratch plan (dead until decode_scatter; WdT8 rows deferred)
  char* hb = (char*)H;
  unsigned short* P      = (unsigned short*)hb;
  char* U                = hb + (size_t)NT*DH*2;
  unsigned short* Xh     = (unsigned short*)U;
  unsigned short* Wench  = (unsigned short*)(U + (size_t)NT*DI*2);
  unsigned short* Wskiph = (unsigned short*)(U + (size_t)NT*DI*2 + (size_t)DH*DI*2);
  unsigned char*  WdT8   = (unsigned char*)(U + (size_t)NT*DI*2 + (size_t)DH*DI*2 + (size_t)DO*DI*2);

  int*   candIdx    = (int*)d_ws;
  float* candVal    = (float*)((char*)d_ws + (size_t)NT*KSEL*4);
  float* lossPartial= (float*)((char*)d_ws + (size_t)NT*KSEL*8);

  k_cvt<<<NT*DI/8/256, 256, 0, stream>>>(X, Xh, NT*DI/8);
  k_cvt<<<DH*DI/8/256, 256, 0, stream>>>(Wenc, Wench, DH*DI/8);
  k_cvt<<<DO*DI/8/256, 256, 0, stream>>>(Wskip, Wskiph, DO*DI/8);
  k_transpose_cvt8<<<dim3(DO/64, DH/64), 256, 0, stream>>>(Wdec, WdT8);

  k_gemm_enc8<<<dim3(NT/256, DH/256), 512, 0, stream>>>(Xh, Wench, benc, P);
  k_topk<<<NT, 256, 0, stream>>>(P, X, Wenc, benc, candIdx, candVal);
  k_gemm_skip8<<<dim3(NT/256, DO/256), 512, 0, stream>>>(Xh, Wskiph, bdec, bskip, outhat);
  k_decode_scatter<<<NT, 256, 0, stream>>>(outhat, H, WdT8, candIdx, candVal, tgt, lossPartial);
  k_scatter_fix<<<WDT_ROW_HI - WDT_ROW_LO, 256, 0, stream>>>(H, candIdx, candVal);
  k_lossreduce<<<1, 256, 0, stream>>>(lossPartial, lossOut);
}

// Round 20
// 1141.911 us; speedup vs baseline: 1.8656x; 1.0041x over previous
//
#include <hip/hip_runtime.h>
#include <stdint.h>

#define NT   8192
#define DI   2048
#define DH   16384
#define DO   2048
#define KSEL 64
#define EPS_SEL 0.004f
#define BCAP 256
// h rows physically hosting WdT8 (byte range [360MB, 392MB) of the h region)
#define WDT_ROW_LO 5760
#define WDT_ROW_HI 6272

typedef _Float16 f16;
typedef f16  f16x8 __attribute__((ext_vector_type(8)));
typedef float f32x4 __attribute__((ext_vector_type(4)));
typedef unsigned short usx8 __attribute__((ext_vector_type(8)));

__device__ __forceinline__ unsigned short f2h_bits(float x){
  f16 h = (f16)x;
  union { f16 h; unsigned short u; } c; c.h = h; return c.u;
}
__device__ __forceinline__ float h_bits2f(unsigned short u){
  union { unsigned short u; f16 h; } c; c.u = u; return (float)c.h;
}
__device__ __forceinline__ unsigned char f2fp8(float x){
  return (unsigned char)(__builtin_amdgcn_cvt_pk_fp8_f32(x, 0.f, 0u, false) & 0xff);
}

__device__ __forceinline__ void gload16(const void* g, void* lds){
  __builtin_amdgcn_global_load_lds(
    (const __attribute__((address_space(1))) void*)(uintptr_t)g,
    (__attribute__((address_space(3))) void*)(uint32_t)(uintptr_t)lds,
    16, 0, 0);
}

// ---------------- f32 -> f16 convert (vector8) ----------------
__global__ __launch_bounds__(256) void k_cvt(const float* __restrict__ in,
                                             unsigned short* __restrict__ out, int n8)
{
  int i = blockIdx.x*256 + threadIdx.x;
  if (i >= n8) return;
  const float4* p = (const float4*)in + (size_t)i*2;
  float4 a = p[0], b = p[1];
  union { f16 h[8]; usx8 u; } r;
  r.h[0]=(f16)a.x; r.h[1]=(f16)a.y; r.h[2]=(f16)a.z; r.h[3]=(f16)a.w;
  r.h[4]=(f16)b.x; r.h[5]=(f16)b.y; r.h[6]=(f16)b.z; r.h[7]=(f16)b.w;
  ((usx8*)out)[i] = r.u;
}

// -------- W_dec [DO][DH] f32 -> WdecT8 [DH][DO] fp8 e4m3, pre-scaled x64 -----
__global__ __launch_bounds__(256) void k_transpose_cvt8(const float* __restrict__ W,
                                                        unsigned char* __restrict__ WT)
{
  __shared__ unsigned char t[64][68];
  const int r0 = blockIdx.x*64;   // over DO
  const int c0 = blockIdx.y*64;   // over DH
  const int tid = threadIdx.x;
  const int q = tid >> 6, s = tid & 63;
#pragma unroll
  for (int i=0;i<16;i++){
    int r = q + i*4;
    t[r][s] = f2fp8(W[(size_t)(r0+r)*DH + c0 + s] * 64.0f);
  }
  __syncthreads();
#pragma unroll
  for (int i=0;i<16;i++){
    int c = q + i*4;
    WT[(size_t)(c0+c)*DO + r0 + s] = t[s][c];
  }
}

// ============ 256^2 8-phase GEMM template (R14-proven) ============
template<bool F16OUT, bool HASB2>
__device__ __forceinline__ void gemm8_body(
    const unsigned short* __restrict__ Ap,
    const unsigned short* __restrict__ Bp,
    const float* __restrict__ bias1,
    const float* __restrict__ bias2,
    void* __restrict__ Cout, int N)
{
  __shared__ unsigned short lds[65536];   // 128 KB
  const int tid  = threadIdx.x;
  const int lane = tid & 63;
  const int wv   = tid >> 6;
  const int wm   = wv >> 2;     // 0..1
  const int wn   = wv & 3;      // 0..3
  const int bm   = blockIdx.x;  // fastest -> B-panel reuse (R5-proven)
  const int bn   = blockIdx.y;
  const int fr   = lane & 15;
  const int fq   = lane >> 4;

  f32x4 acc[8][4];
#pragma unroll
  for (int i=0;i<8;i++)
#pragma unroll
    for (int j=0;j<4;j++) acc[i][j] = (f32x4){0.f,0.f,0.f,0.f};

  f16x8 ar[4][2];
  f16x8 br[2][2];

#define STAGE_HALF(t, ab, h) do { \
    const unsigned short* G_ = (ab) ? Bp : Ap; \
    const int rb_ = ((ab) ? bn : bm)*256 + (h)*128; \
    const int k0_ = (t)*64; \
    const int db_ = ((t)&1)*32768 + (ab)*16384 + (h)*8192; \
    _Pragma("unroll") \
    for (int is_=0; is_<2; ++is_){ \
      const int cw_ = wv*64 + is_*512; \
      const int cl_ = cw_ + lane; \
      const int cs_ = cl_ ^ ((cl_>>3)&7); \
      gload16(G_ + (size_t)(rb_ + (cs_>>3))*DI + k0_ + (cs_&7)*8, \
              (unsigned short*)lds + db_ + cw_*8); \
    } } while(0)

#define LD_A(buf, mh) do { \
    const int ba_ = (buf)*32768 + (mh)*8192; \
    _Pragma("unroll") \
    for (int mf_=0; mf_<4; ++mf_) \
    _Pragma("unroll") \
    for (int ks_=0; ks_<2; ++ks_){ \
      const int lin_ = (wm*64 + mf_*16 + fr)*128 + (ks_*4 + fq)*16; \
      const int sz_  = lin_ ^ ((((lin_>>7)&7))<<4); \
      ar[mf_][ks_] = *(const f16x8*)&lds[ba_ + (sz_>>1)]; \
    } } while(0)

#define LD_B(buf, nh) do { \
    const int bb_ = (buf)*32768 + 16384 + (nh)*8192; \
    _Pragma("unroll") \
    for (int nf_=0; nf_<2; ++nf_) \
    _Pragma("unroll") \
    for (int ks_=0; ks_<2; ++ks_){ \
      const int lin_ = (wn*32 + nf_*16 + fr)*128 + (ks_*4 + fq)*16; \
      const int sz_  = lin_ ^ ((((lin_>>7)&7))<<4); \
      br[nf_][ks_] = *(const f16x8*)&lds[bb_ + (sz_>>1)]; \
    } } while(0)

#define MM(mh, nh) do { \
    _Pragma("unroll") \
    for (int mf_=0; mf_<4; ++mf_) \
    _Pragma("unroll") \
    for (int nf_=0; nf_<2; ++nf_) \
    _Pragma("unroll") \
    for (int ks_=0; ks_<2; ++ks_) \
      acc[(mh)*4+mf_][(nh)*2+nf_] = __builtin_amdgcn_mfma_f32_16x16x32_f16( \
          ar[mf_][ks_], br[nf_][ks_], acc[(mh)*4+mf_][(nh)*2+nf_], 0, 0, 0); \
  } while(0)

#define VM6 asm volatile("s_waitcnt vmcnt(6)" ::: "memory")
#define VM0 asm volatile("s_waitcnt vmcnt(0)" ::: "memory")

#define PH(buf, mh, nh, LA_, LB_, STG, VM) do { \
    if (LA_) LD_A(buf, mh); \
    if (LB_) LD_B(buf, nh); \
    STG; \
    VM; \
    __builtin_amdgcn_s_barrier(); \
    asm volatile("s_waitcnt lgkmcnt(0)" ::: "memory"); \
    __builtin_amdgcn_sched_barrier(0); \
    __builtin_amdgcn_s_setprio(1); \
    MM(mh, nh); \
    __builtin_amdgcn_s_setprio(0); \
  } while(0)

  STAGE_HALF(0,0,0); STAGE_HALF(0,1,1); STAGE_HALF(0,0,1); STAGE_HALF(0,1,0);
  STAGE_HALF(1,0,0); STAGE_HALF(1,1,1); STAGE_HALF(1,0,1);
  asm volatile("s_waitcnt vmcnt(6)" ::: "memory");
  __builtin_amdgcn_s_barrier();

  for (int j = 0; j < 15; ++j) {
    const int a = 2*j, b = 2*j+1;
    PH(0, 0,0, 1,1, STAGE_HALF(b,  1,0), (void)0);
    PH(0, 0,1, 0,1, STAGE_HALF(a+2,0,0), (void)0);
    PH(0, 1,1, 1,0, STAGE_HALF(a+2,1,1), (void)0);
    PH(0, 1,0, 0,1, STAGE_HALF(a+2,0,1), VM6);
    PH(1, 0,0, 1,1, STAGE_HALF(a+2,1,0), (void)0);
    PH(1, 0,1, 0,1, STAGE_HALF(b+2,0,0), (void)0);
    PH(1, 1,1, 1,0, STAGE_HALF(b+2,1,1), (void)0);
    PH(1, 1,0, 0,1, STAGE_HALF(b+2,0,1), VM6);
  }
  PH(0, 0,0, 1,1, STAGE_HALF(31,1,0), (void)0);
  PH(0, 0,1, 0,1, (void)0, (void)0);
  PH(0, 1,1, 1,0, (void)0, (void)0);
  PH(0, 1,0, 0,1, (void)0, VM0);
  PH(1, 0,0, 1,1, (void)0, (void)0);
  PH(1, 0,1, 0,1, (void)0, (void)0);
  PH(1, 1,1, 1,0, (void)0, (void)0);
  PH(1, 1,0, 0,1, (void)0, (void)0);

#undef PH
#undef VM6
#undef VM0
#undef MM
#undef LD_B
#undef LD_A
#undef STAGE_HALF

  // direct-store epilogue (R8/R9-proven)
#pragma unroll
  for (int nh=0; nh<2; ++nh)
#pragma unroll
  for (int nf=0; nf<2; ++nf){
    const int col = bn*256 + nh*128 + wn*32 + nf*16 + fr;
    float bs = bias1[col];
    if (HASB2) bs += bias2[col];
#pragma unroll
    for (int mh=0; mh<2; ++mh)
#pragma unroll
    for (int mf=0; mf<4; ++mf){
      const int row0 = bm*256 + mh*128 + wm*64 + mf*16 + fq*4;
#pragma unroll
      for (int q=0; q<4; ++q){
        float v = acc[mh*4+mf][nh*2+nf][q] + bs;
        if (F16OUT) ((unsigned short*)Cout)[(size_t)(row0+q)*N + col] = f2h_bits(v);
        else        ((float*)Cout)[(size_t)(row0+q)*N + col] = v;
      }
    }
  }
}

__global__ __launch_bounds__(512, 2) void k_gemm_enc8(
    const unsigned short* __restrict__ Ap, const unsigned short* __restrict__ Bp,
    const float* __restrict__ bias, unsigned short* __restrict__ C)
{
  gemm8_body<true, false>(Ap, Bp, bias, nullptr, (void*)C, DH);
}

__global__ __launch_bounds__(512, 2) void k_gemm_skip8(
    const unsigned short* __restrict__ Ap, const unsigned short* __restrict__ Bp,
    const float* __restrict__ bias1, const float* __restrict__ bias2,
    float* __restrict__ C)
{
  gemm8_body<false, true>(Ap, Bp, bias1, bias2, (void*)C, DO);
}

// ---------------- exact top-64 per row ----------------
// R19: band phase stages Xr once into LDS (aliasing the then-dead hist16
// storage; 8KB of 16.4KB) -> removes ~6x global X re-reads and frees L1 for
// the Wenc gather rows. Numerics bit-identical ((double) of the same f32).
__global__ __launch_bounds__(256) void k_topk(
    const unsigned short* __restrict__ P,
    const float* __restrict__ X,
    const float* __restrict__ Wenc,
    const float* __restrict__ benc,
    int*   __restrict__ candIdx,
    float* __restrict__ candVal)
{
  __shared__ unsigned int hist16[16][257];
  __shared__ unsigned int hist2[257];
  __shared__ int   inIdx[64];
  __shared__ float inVal[64];
  __shared__ int    bandIdx[BCAP];
  __shared__ double bandVal[BCAP];
  __shared__ int s_inCnt, s_bandCnt, s_sel, s_above, s_sel2;

  const int r = blockIdx.x;
  const int tid = threadIdx.x;
  const int wv = tid >> 6, lane = tid & 63;
  const int lc = lane & 15;
  const unsigned short* Prow = P + (size_t)r*DH;

#pragma unroll
  for (int k=0;k<16;k++) hist16[k][tid] = 0;
  hist2[tid] = 0;
  if (tid==0){ s_inCnt=0; s_bandCnt=0; }

  const usx8* Pv = (const usx8*)Prow;
  usx8 c0 = Pv[tid];        usx8 c1 = Pv[tid+256];
  usx8 c2 = Pv[tid+512];    usx8 c3 = Pv[tid+768];
  usx8 c4 = Pv[tid+1024];   usx8 c5 = Pv[tid+1280];
  usx8 c6 = Pv[tid+1536];   usx8 c7 = Pv[tid+1792];
  __syncthreads();

#define OMAP(b) (unsigned short)(((b) & 0x8000) ? (unsigned short)~(b) : (unsigned short)((b)|0x8000))
#define H1(CC) { _Pragma("unroll") for (int e=0;e<8;e++){ \
    unsigned short o = OMAP(CC[e]); atomicAdd(&hist16[lc][o>>8], 1u); } }
  H1(c0) H1(c1) H1(c2) H1(c3) H1(c4) H1(c5) H1(c6) H1(c7)
#undef H1
  __syncthreads();
  {
    unsigned int hs = 0;
#pragma unroll
    for (int c=0;c<16;c++) hs += hist16[c][tid];
    hist16[0][tid] = hs;
  }
  __syncthreads();

  if (tid < 64) {
    const int h0 = 255 - 4*tid;
    unsigned int c0_=hist16[0][h0], c1_=hist16[0][h0-1], c2_=hist16[0][h0-2], c3_=hist16[0][h0-3];
    unsigned int s = c0_+c1_+c2_+c3_;
    unsigned int Pi = s;
#pragma unroll
    for (int off=1; off<64; off<<=1){
      unsigned int t = __shfl_up(Pi, off);
      if (tid >= off) Pi += t;
    }
    unsigned long long mk = __ballot(Pi >= KSEL);
    int cr = (int)__builtin_ctzll(mk);
    if (tid == cr){
      unsigned int cum = Pi - s;
      unsigned int cc[4] = {c0_,c1_,c2_,c3_};
#pragma unroll
      for (int j=0;j<4;j++){
        if (cum + cc[j] >= KSEL){ s_sel = h0-j; s_above = (int)cum; break; }
        cum += cc[j];
      }
    }
  }
  __syncthreads();
  const int bsel = s_sel; const int cntAbove = s_above;

  // hist16 is dead from here: alias its storage to stage the X row (f32[2048]).
  // Loads issued now; latency hides under pass-2 + extraction. First read of
  // xs is after the next-but-one __syncthreads (band phase).
  float* xs = (float*)&hist16[0][0];
  {
    const float* Xg = X + (size_t)r*DI;
#pragma unroll
    for (int i=0;i<8;i++) xs[tid + i*256] = Xg[tid + i*256];
  }

#define H2(CC) { _Pragma("unroll") for (int e=0;e<8;e++){ \
    unsigned short o = OMAP(CC[e]); \
    if ((int)(o>>8) == bsel) atomicAdd(&hist2[o & 0xff], 1u); } }
  H2(c0) H2(c1) H2(c2) H2(c3) H2(c4) H2(c5) H2(c6) H2(c7)
#undef H2
  __syncthreads();
  {
    const int K2 = KSEL - cntAbove;
    if (tid < 64) {
      const int h0 = 255 - 4*tid;
      unsigned int c0_=hist2[h0], c1_=hist2[h0-1], c2_=hist2[h0-2], c3_=hist2[h0-3];
      unsigned int s = c0_+c1_+c2_+c3_;
      unsigned int Pi = s;
#pragma unroll
      for (int off=1; off<64; off<<=1){
        unsigned int t = __shfl_up(Pi, off);
        if (tid >= off) Pi += t;
      }
      unsigned long long mk = __ballot(Pi >= (unsigned)K2);
      int cr = (int)__builtin_ctzll(mk);
      if (tid == cr){
        unsigned int cum = Pi - s;
        unsigned int cc[4] = {c0_,c1_,c2_,c3_};
#pragma unroll
        for (int j=0;j<4;j++){
          if (cum + cc[j] >= (unsigned)K2){ s_sel2 = h0-j; break; }
          cum += cc[j];
        }
      }
    }
  }
  __syncthreads();

  unsigned short To = (unsigned short)((bsel<<8) | s_sel2);
  unsigned short tb = (To & 0x8000) ? (unsigned short)(To ^ 0x8000) : (unsigned short)~To;
  const float T = h_bits2f(tb);
  const float hiv = T + 2.0f*EPS_SEL, lov = T - 2.0f*EPS_SEL;

#define EXT(CC, KK) { _Pragma("unroll") for (int e=0;e<8;e++){ \
    float v = h_bits2f(CC[e]); \
    if (v > hiv){ \
      int p = atomicAdd(&s_inCnt,1); \
      if (p < 64){ inIdx[p] = (tid + (KK)*256)*8 + e; inVal[p] = v; } \
    } else if (v >= lov){ \
      int p = atomicAdd(&s_bandCnt,1); \
      if (p < BCAP) bandIdx[p] = (tid + (KK)*256)*8 + e; \
    } } }
  EXT(c0,0) EXT(c1,1) EXT(c2,2) EXT(c3,3) EXT(c4,4) EXT(c5,5) EXT(c6,6) EXT(c7,7)
#undef EXT
#undef OMAP
  __syncthreads();
  const int m = s_inCnt < 64 ? s_inCnt : 64;
  const int B = s_bandCnt < BCAP ? s_bandCnt : BCAP;

  // exact f64 recompute for ambiguous band; X from LDS, Wenc gathered
  for (int b=wv; b<B; b+=4){
    const int j = bandIdx[b];
    const float* Wr = Wenc + (size_t)j*DI;
    double s0=0.0, s1=0.0, s2=0.0, s3=0.0;
    for (int k0=lane; k0<DI; k0+=256){
      s0 = fma((double)xs[k0],     (double)Wr[k0],     s0);
      s1 = fma((double)xs[k0+64],  (double)Wr[k0+64],  s1);
      s2 = fma((double)xs[k0+128], (double)Wr[k0+128], s2);
      s3 = fma((double)xs[k0+192], (double)Wr[k0+192], s3);
    }
    double s = (s0+s1)+(s2+s3);
#pragma unroll
    for (int off=32; off>=1; off>>=1) s += __shfl_down(s, off);
    if (lane==0) bandVal[b] = s + (double)benc[j];
  }
  __syncthreads();

  int* ci = candIdx + (size_t)r*KSEL;
  float* cv = candVal + (size_t)r*KSEL;
  for (int t=tid; t<m; t+=256){ ci[t]=inIdx[t]; cv[t]=inVal[t]; }

  const int need = KSEL - m;
  if (tid < 64 && need > 0){
    unsigned int used = 0;
    for (int t=0;t<need;t++){
      double best = -1.0e300; int bi = -1;
#pragma unroll
      for (int sIt=0;sIt<4;sIt++){
        int b = tid + sIt*64;
        if (b < B && !((used>>sIt)&1)){
          double v = bandVal[b];
          if (v > best){ best=v; bi=b; }
        }
      }
#pragma unroll
      for (int off=32; off>=1; off>>=1){
        double ov = __shfl_down(best, off);
        int    oi = __shfl_down(bi,   off);
        if (ov > best){ best = ov; bi = oi; }
      }
      bi   = __shfl(bi, 0);
      best = __shfl(best, 0);
      if ((bi & 63) == tid) used |= 1u << (bi >> 6);
      if (tid == 0){
        ci[m+t] = bandIdx[bi];
        cv[m+t] = (float)best;
      }
    }
  }
}

// ------- merged sparse decode (fp8 gather) + loss partial + h scatter -------
__global__ __launch_bounds__(256) void k_decode_scatter(
    float* __restrict__ outhat,
    float* __restrict__ H,
    const unsigned char* __restrict__ WdT8,
    const int*   __restrict__ candIdx,
    const float* __restrict__ candVal,
    const float* __restrict__ target,
    float* __restrict__ lossPartial)
{
  __shared__ int   sIdx[KSEL];
  __shared__ float sVal[KSEL];   // relu'd raw value (for h scatter)
  __shared__ float wsum[4];
  const int r = blockIdx.x, tid = threadIdx.x;
  if (tid < KSEL){
    sIdx[tid]=candIdx[(size_t)r*KSEL+tid];
    float v=candVal[(size_t)r*KSEL+tid];
    sVal[tid] = v>0.f ? v : 0.f;
  }
  const bool doScatter = (r < WDT_ROW_LO) || (r >= WDT_ROW_HI);
  float* hr = H + (size_t)r*DH;
  if (doScatter){
    const float4 z = {0.f,0.f,0.f,0.f};
#pragma unroll
    for (int i=0;i<16;i++) ((float4*)hr)[tid + i*256] = z;
  }
  __syncthreads();
  float* orow = outhat + (size_t)r*DO;
  float a[8];
  {
    float4 v0 = *(const float4*)(orow + tid*8);
    float4 v1 = *(const float4*)(orow + tid*8 + 4);
    a[0]=v0.x;a[1]=v0.y;a[2]=v0.z;a[3]=v0.w;a[4]=v1.x;a[5]=v1.y;a[6]=v1.z;a[7]=v1.w;
  }
#pragma unroll 4
  for (int c=0;c<KSEL;c++){
    const float v = sVal[c] * 0.015625f;   // /64 descale
    const uint2 w = *(const uint2*)(WdT8 + (size_t)sIdx[c]*DO + tid*8);
    a[0] = fmaf(v, __builtin_amdgcn_cvt_f32_fp8(w.x, 0), a[0]);
    a[1] = fmaf(v, __builtin_amdgcn_cvt_f32_fp8(w.x, 1), a[1]);
    a[2] = fmaf(v, __builtin_amdgcn_cvt_f32_fp8(w.x, 2), a[2]);
    a[3] = fmaf(v, __builtin_amdgcn_cvt_f32_fp8(w.x, 3), a[3]);
    a[4] = fmaf(v, __builtin_amdgcn_cvt_f32_fp8(w.y, 0), a[4]);
    a[5] = fmaf(v, __builtin_amdgcn_cvt_f32_fp8(w.y, 1), a[5]);
    a[6] = fmaf(v, __builtin_amdgcn_cvt_f32_fp8(w.y, 2), a[6]);
    a[7] = fmaf(v, __builtin_amdgcn_cvt_f32_fp8(w.y, 3), a[7]);
  }
  const float* trow = target + (size_t)r*DO;
  float4 t0 = *(const float4*)(trow + tid*8);
  float4 t1 = *(const float4*)(trow + tid*8 + 4);
  float tt[8] = {t0.x,t0.y,t0.z,t0.w,t1.x,t1.y,t1.z,t1.w};
  float ls = 0.f;
#pragma unroll
  for (int j=0;j<8;j++){ float d = a[j]-tt[j]; ls = fmaf(d,d,ls); }
  {
    float4 v0 = {a[0],a[1],a[2],a[3]}, v1 = {a[4],a[5],a[6],a[7]};
    *(float4*)(orow + tid*8) = v0;
    *(float4*)(orow + tid*8 + 4) = v1;
  }
#pragma unroll
  for (int off=32; off>=1; off>>=1) ls += __shfl_down(ls, off);
  if ((tid&63)==0) wsum[tid>>6]=ls;
  __syncthreads();
  if (tid==0)
    lossPartial[r] = (wsum[0]+wsum[1]+wsum[2]+wsum[3]) * (1.0f/((float)NT*(float)DO));
  if (doScatter && tid < KSEL)
    hr[sIdx[tid]] = sVal[tid];
}

// ---- deferred scatter for the 512 rows that hosted WdT8 ----
__global__ __launch_bounds__(256) void k_scatter_fix(
    float* __restrict__ H, const int* __restrict__ candIdx, const float* __restrict__ candVal)
{
  const int r = WDT_ROW_LO + blockIdx.x, tid = threadIdx.x;
  float* hr = H + (size_t)r*DH;
  const float4 z = {0.f,0.f,0.f,0.f};
#pragma unroll
  for (int i=0;i<16;i++) ((float4*)hr)[tid + i*256] = z;
  __syncthreads();
  if (tid<KSEL){
    float v = candVal[(size_t)r*KSEL+tid];
    hr[candIdx[(size_t)r*KSEL+tid]] = v>0.f ? v : 0.f;
  }
}

__global__ __launch_bounds__(256) void k_lossreduce(const float* __restrict__ lp,
                                                    float* __restrict__ out)
{
  __shared__ double ws[4];
  double s=0.0;
  for (int i=threadIdx.x;i<NT;i+=256) s += (double)lp[i];
#pragma unroll
  for (int off=32; off>=1; off>>=1) s += __shfl_down(s, off);
  if ((threadIdx.x&63)==0) ws[threadIdx.x>>6]=s;
  __syncthreads();
  if (threadIdx.x==0) *out = (float)(ws[0]+ws[1]+ws[2]+ws[3]);
}

extern "C" void kernel_launch(void* const* d_in, const int* in_sizes, int n_in,
                              void* d_out, int out_size, void* d_ws, size_t ws_size,
                              hipStream_t stream)
{
  const float* X     = (const float*)d_in[0];
  const float* tgt   = (const float*)d_in[1];
  const float* Wenc  = (const float*)d_in[2];
  const float* benc  = (const float*)d_in[3];
  const float* Wdec  = (const float*)d_in[4];
  const float* bdec  = (const float*)d_in[5];
  const float* Wskip = (const float*)d_in[6];
  const float* bskip = (const float*)d_in[7];

  float* out     = (float*)d_out;
  float* outhat  = out;
  float* H       = out + (size_t)NT*DO;
  float* lossOut = out + (size_t)NT*DO + (size_t)NT*DH;

  // h-region scratch plan (dead until decode_scatter; WdT8 rows deferred)
  char* hb = (char*)H;
  unsigned short* P      = (unsigned short*)hb;
  char* U                = hb + (size_t)NT*DH*2;
  unsigned short* Xh     = (unsigned short*)U;
  unsigned short* Wench  = (unsigned short*)(U + (size_t)NT*DI*2);
  unsigned short* Wskiph = (unsigned short*)(U + (size_t)NT*DI*2 + (size_t)DH*DI*2);
  unsigned char*  WdT8   = (unsigned char*)(U + (size_t)NT*DI*2 + (size_t)DH*DI*2 + (size_t)DO*DI*2);

  int*   candIdx    = (int*)d_ws;
  float* candVal    = (float*)((char*)d_ws + (size_t)NT*KSEL*4);
  float* lossPartial= (float*)((char*)d_ws + (size_t)NT*KSEL*8);

  k_cvt<<<NT*DI/8/256, 256, 0, stream>>>(X, Xh, NT*DI/8);
  k_cvt<<<DH*DI/8/256, 256, 0, stream>>>(Wenc, Wench, DH*DI/8);
  k_cvt<<<DO*DI/8/256, 256, 0, stream>>>(Wskip, Wskiph, DO*DI/8);
  k_transpose_cvt8<<<dim3(DO/64, DH/64), 256, 0, stream>>>(Wdec, WdT8);

  k_gemm_enc8<<<dim3(NT/256, DH/256), 512, 0, stream>>>(Xh, Wench, benc, P);
  k_topk<<<NT, 256, 0, stream>>>(P, X, Wenc, benc, candIdx, candVal);
  k_gemm_skip8<<<dim3(NT/256, DO/256), 512, 0, stream>>>(Xh, Wskiph, bdec, bskip, outhat);
  k_decode_scatter<<<NT, 256, 0, stream>>>(outhat, H, WdT8, candIdx, candVal, tgt, lossPartial);
  k_scatter_fix<<<WDT_ROW_HI - WDT_ROW_LO, 256, 0, stream>>>(H, candIdx, candVal);
  k_lossreduce<<<1, 256, 0, stream>>>(lossPartial, lossOut);
}